// Round 1
// baseline (1346.744 us; speedup 1.0000x reference)
//
#include <hip/hip_runtime.h>
#include <cstddef>
#include <cstdint>

#define NN 50000
#define NE 600000
#define H 128
#define NG 512
#define OUTC 128
#define EPSV 1e-5f

// ---------------- utility kernels ----------------
__global__ void k_fill_int(int* p, int v, int n) {
  int i = blockIdx.x * blockDim.x + threadIdx.x;
  if (i < n) p[i] = v;
}
__global__ void k_zero_f(float* p, int n) {
  int i = blockIdx.x * blockDim.x + threadIdx.x;
  if (i < n) p[i] = 0.f;
}
__global__ void k_copy_f(float* dst, const float* src, int n) {
  int i = blockIdx.x * blockDim.x + threadIdx.x;
  if (i < n) dst[i] = src[i];
}
__global__ void k_add_f(float* dst, const float* src, int n) {
  int i = blockIdx.x * blockDim.x + threadIdx.x;
  if (i < n) dst[i] += src[i];
}
__global__ void k_vn_init(const float* __restrict__ vn_emb, float* vn) {
  int i = blockIdx.x * blockDim.x + threadIdx.x;
  if (i < NG * H) vn[i] = vn_emb[i & (H - 1)];
}

// ---------------- graph preprocessing ----------------
__global__ void k_hist_edges(const int* __restrict__ dst, int* deg) {
  int e = blockIdx.x * blockDim.x + threadIdx.x;
  if (e < NE) atomicAdd(&deg[dst[e]], 1);
}
__global__ void k_hist_batch(const int* __restrict__ batch, int* gcnt) {
  int n = blockIdx.x * blockDim.x + threadIdx.x;
  if (n < NN) atomicAdd(&gcnt[batch[n]], 1);
}
__global__ void k_dinv(const int* __restrict__ deg, float* dinv) {
  int i = blockIdx.x * blockDim.x + threadIdx.x;
  if (i < NN) dinv[i] = rsqrtf((float)deg[i]);  // deg >= 1 (self-loop)
}
// exclusive scan of (deg[i]-1) over NN elements, single block of 1024 threads
__global__ void k_scan(const int* __restrict__ deg, int* __restrict__ rowptr) {
  __shared__ int part[1024];
  int tid = threadIdx.x;
  const int n = NN;
  int chunk = (n + 1023) / 1024;
  int start = tid * chunk;
  int end = start + chunk; if (end > n) end = n;
  int s = 0;
  for (int i = start; i < end; i++) s += deg[i] - 1;
  part[tid] = s;
  __syncthreads();
  for (int off = 1; off < 1024; off <<= 1) {
    int v = 0;
    if (tid >= off) v = part[tid - off];
    __syncthreads();
    if (tid >= off) part[tid] += v;
    __syncthreads();
  }
  int run = (tid == 0) ? 0 : part[tid - 1];
  for (int i = start; i < end; i++) { rowptr[i] = run; run += deg[i] - 1; }
  if (tid == 1023) rowptr[n] = part[1023];
}
__global__ void k_fill_csr(const int* __restrict__ src, const int* __restrict__ dst,
                           const float* __restrict__ dinv, const int* __restrict__ rowptr,
                           int* cursor, int* __restrict__ csr_src, float* __restrict__ csr_norm) {
  int e = blockIdx.x * blockDim.x + threadIdx.x;
  if (e >= NE) return;
  int s = src[e], d = dst[e];
  int pos = rowptr[d] + atomicAdd(&cursor[d], 1);
  csr_src[pos] = s;
  csr_norm[pos] = dinv[s] * dinv[d];
}

// ---------------- propagation: out[d] = scale*(A_hat h)[d] + alpha*base[d] ----------------
__global__ void k_prop(const float* __restrict__ h, const float* __restrict__ base,
                       float* __restrict__ out, const int* __restrict__ rowptr,
                       const int* __restrict__ csr_src, const float* __restrict__ csr_norm,
                       const float* __restrict__ dinv, float scale, float alpha) {
  int d = blockIdx.x;
  int c = threadIdx.x;
  float dv = dinv[d];
  size_t drow = (size_t)d * H;
  float acc = dv * dv * h[drow + c];
  int e = rowptr[d], e1 = rowptr[d + 1];
  for (; e + 1 < e1; e += 2) {
    int sA = csr_src[e], sB = csr_src[e + 1];
    float nA = csr_norm[e], nB = csr_norm[e + 1];
    float vA = h[(size_t)sA * H + c];
    float vB = h[(size_t)sB * H + c];
    acc += nA * vA;
    acc += nB * vB;
  }
  if (e < e1) acc += csr_norm[e] * h[(size_t)csr_src[e] * H + c];
  float r = scale * acc;
  if (base) r += alpha * base[drow + c];
  out[drow + c] = r;
}

// ---------------- node-level matmul: Y[nrows x 128] = X @ W + bias ----------------
__global__ __launch_bounds__(256) void k_mm_node(const float* __restrict__ X,
    const float* __restrict__ Wg, const float* __restrict__ bias,
    float* __restrict__ Y, int nrows) {
  __shared__ float Wl[64 * H];   // 32KB k-tile of W
  __shared__ float Xl[32 * 64];  // 8KB x-tile
  int t = threadIdx.x;
  int rbase = blockIdx.x * 32;
  int cg = t & 15, rg = t >> 4;
  int c0 = cg * 8, r0 = rg * 2;
  float acc[2][8];
#pragma unroll
  for (int j = 0; j < 8; j++) { float bb = bias[c0 + j]; acc[0][j] = bb; acc[1][j] = bb; }
  for (int kt = 0; kt < 2; kt++) {
    __syncthreads();
    {
      const float4* Wv = (const float4*)Wg;
      float4* Wlv = (float4*)Wl;
#pragma unroll
      for (int i = 0; i < 8; i++) {
        int idx = t + i * 256;            // 0..2047
        Wlv[idx] = Wv[kt * 2048 + idx];   // rows kt*64..kt*64+63, all 128 cols
      }
    }
    {
      float4* Xlv = (float4*)Xl;
#pragma unroll
      for (int i = 0; i < 2; i++) {
        int idx = t + i * 256;            // 0..511
        int r = idx >> 4, q = idx & 15;
        float4 v = make_float4(0.f, 0.f, 0.f, 0.f);
        int gr = rbase + r;
        if (gr < nrows) v = ((const float4*)X)[(size_t)gr * 32 + kt * 16 + q];
        Xlv[idx] = v;
      }
    }
    __syncthreads();
#pragma unroll 8
    for (int k = 0; k < 64; k++) {
      float x0 = Xl[r0 * 64 + k];
      float x1 = Xl[(r0 + 1) * 64 + k];
      float4 w0 = ((const float4*)Wl)[k * 32 + (c0 >> 2)];
      float4 w1 = ((const float4*)Wl)[k * 32 + (c0 >> 2) + 1];
      float w[8] = {w0.x, w0.y, w0.z, w0.w, w1.x, w1.y, w1.z, w1.w};
#pragma unroll
      for (int j = 0; j < 8; j++) { acc[0][j] += x0 * w[j]; acc[1][j] += x1 * w[j]; }
    }
  }
#pragma unroll
  for (int rr = 0; rr < 2; rr++) {
    int gr = rbase + r0 + rr;
    if (gr < nrows) {
      float4* dst = (float4*)&Y[(size_t)gr * H + c0];
      dst[0] = make_float4(acc[rr][0], acc[rr][1], acc[rr][2], acc[rr][3]);
      dst[1] = make_float4(acc[rr][4], acc[rr][5], acc[rr][6], acc[rr][7]);
    }
  }
}

// ---------------- column stats (sum, sumsq) via block partials + atomics ----------------
__global__ void k_colstats(const float* __restrict__ X, int nrows, int ncols, float* stats) {
  int c = threadIdx.x;  // blockDim.x == ncols
  int rows_per = (nrows + gridDim.x - 1) / gridDim.x;
  int r0 = blockIdx.x * rows_per;
  int r1 = r0 + rows_per; if (r1 > nrows) r1 = nrows;
  float s = 0.f, ss = 0.f;
  for (int r = r0; r < r1; r++) {
    float v = X[(size_t)r * ncols + c];
    s += v; ss += v * v;
  }
  atomicAdd(&stats[c], s);
  atomicAdd(&stats[ncols + c], ss);
}

// ---------------- BN (+relu) + virtual-node add + vt segment-sum ----------------
__global__ void k_bn_vn(const float* __restrict__ X, const float* __restrict__ stats,
                        const float* __restrict__ g, const float* __restrict__ bt,
                        const float* __restrict__ vn, const int* __restrict__ batch,
                        float* __restrict__ out, float* __restrict__ vt) {
  int idx = blockIdx.x * blockDim.x + threadIdx.x;
  if (idx >= NN * H) return;
  int c = idx & (H - 1);
  int n = idx >> 7;
  const float invN = 1.0f / NN;
  float m = stats[c] * invN;
  float var = stats[H + c] * invN - m * m;
  float rs = rsqrtf(var + EPSV);
  float y = g[c] * (X[idx] - m) * rs + bt[c];
  y = fmaxf(y, 0.f);
  int b = batch[n];
  y += vn[b * H + c];
  out[idx] = y;
  atomicAdd(&vt[b * H + c], y);
}
// BN only (last conv layer, no relu/vn)
__global__ void k_bn_plain(const float* __restrict__ X, const float* __restrict__ stats,
                           const float* __restrict__ g, const float* __restrict__ bt,
                           float* __restrict__ out) {
  int idx = blockIdx.x * blockDim.x + threadIdx.x;
  if (idx >= NN * H) return;
  int c = idx & (H - 1);
  const float invN = 1.0f / NN;
  float m = stats[c] * invN;
  float var = stats[H + c] * invN - m * m;
  float rs = rsqrtf(var + EPSV);
  out[idx] = g[c] * (X[idx] - m) * rs + bt[c];
}
// BN+relu in place for small [nrows x C]
__global__ void k_bn_small(float* Y, const float* __restrict__ stats,
                           const float* __restrict__ g, const float* __restrict__ bt,
                           int nrows, int C) {
  int idx = blockIdx.x * blockDim.x + threadIdx.x;
  if (idx >= nrows * C) return;
  int c = idx % C;
  float invN = 1.0f / nrows;
  float m = stats[c] * invN;
  float var = stats[C + c] * invN - m * m;
  float rs = rsqrtf(var + EPSV);
  Y[idx] = fmaxf(g[c] * (Y[idx] - m) * rs + bt[c], 0.f);
}

// ---------------- small matmul: Y[nrows x M] = X[nrows x K] @ W[K x M] + bias ----------------
__global__ void k_mm_small(const float* __restrict__ X, const float* __restrict__ W,
                           const float* __restrict__ bias, float* __restrict__ Y,
                           int nrows, int K, int M) {
  int idx = blockIdx.x * blockDim.x + threadIdx.x;
  if (idx >= nrows * M) return;
  int r = idx / M, c = idx % M;
  float acc = bias[c];
  const float* xr = X + (size_t)r * K;
  for (int k = 0; k < K; k++) acc += xr[k] * W[(size_t)k * M + c];
  Y[idx] = acc;
}

// ---------------- pooling ----------------
__global__ void k_pool(const float* __restrict__ h, const int* __restrict__ batch,
                       float* pooled) {
  int idx = blockIdx.x * blockDim.x + threadIdx.x;
  if (idx >= NN * H) return;
  int n = idx >> 7, c = idx & (H - 1);
  atomicAdd(&pooled[batch[n] * H + c], h[idx]);
}
__global__ void k_head(const float* __restrict__ pooled, const int* __restrict__ gcnt,
                       const float* __restrict__ Wout, const float* __restrict__ bout,
                       float* __restrict__ out) {
  int idx = blockIdx.x * blockDim.x + threadIdx.x;
  if (idx >= NG * OUTC) return;
  int g = idx / OUTC, c = idx % OUTC;
  float inv = 1.0f / fmaxf((float)gcnt[g], 1.0f);
  float acc = bout[c];
  const float* pr = pooled + (size_t)g * H;
  for (int k = 0; k < H; k++) acc += pr[k] * inv * Wout[(size_t)k * OUTC + c];
  out[idx] = acc;
}

// ---------------- launch ----------------
extern "C" void kernel_launch(void* const* d_in, const int* in_sizes, int n_in,
                              void* d_out, int out_size, void* d_ws, size_t ws_size,
                              hipStream_t stream) {
  const float* x      = (const float*)d_in[0];
  const int*   ei     = (const int*)d_in[1];
  const int*   e_src  = ei;
  const int*   e_dst  = ei + NE;
  const int*   batch  = (const int*)d_in[2];
  const float* W      = (const float*)d_in[3];
  const float* b      = (const float*)d_in[4];
  const float* gamma  = (const float*)d_in[5];
  const float* beta   = (const float*)d_in[6];
  const float* vn_emb = (const float*)d_in[7];
  const float* W1     = (const float*)d_in[8];
  const float* b1     = (const float*)d_in[9];
  const float* g1     = (const float*)d_in[10];
  const float* bt1    = (const float*)d_in[11];
  const float* W2     = (const float*)d_in[12];
  const float* b2     = (const float*)d_in[13];
  const float* g2     = (const float*)d_in[14];
  const float* bt2    = (const float*)d_in[15];
  const float* Wout   = (const float*)d_in[16];
  const float* bout   = (const float*)d_in[17];
  float* out = (float*)d_out;

  char* p = (char*)d_ws;
  auto alloc = [&](size_t bytes) -> char* {
    char* r = p; p += (bytes + 255) & ~(size_t)255; return r;
  };
  float* hA       = (float*)alloc((size_t)NN * H * 4);
  float* hB       = (float*)alloc((size_t)NN * H * 4);
  float* hC       = (float*)alloc((size_t)NN * H * 4);
  int*   deg      = (int*)alloc((size_t)NN * 4);
  int*   cursor   = (int*)alloc((size_t)NN * 4);
  int*   rowptr   = (int*)alloc((size_t)(NN + 1) * 4);
  int*   gcnt     = (int*)alloc(512 * 4);
  int*   csr_src  = (int*)alloc((size_t)NE * 4);
  float* csr_norm = (float*)alloc((size_t)NE * 4);
  float* dinv     = (float*)alloc((size_t)NN * 4);
  float* vn       = (float*)alloc((size_t)NG * H * 4);
  float* vt       = (float*)alloc((size_t)NG * H * 4);
  float* t1       = (float*)alloc((size_t)NG * 256 * 4);
  float* t2       = (float*)alloc((size_t)NG * H * 4);
  float* pooled   = (float*)alloc((size_t)NG * H * 4);
  float* stats    = (float*)alloc(512 * 4);

  const int B = 256;
  const int gNN  = (NN + B - 1) / B;          // 196
  const int gNE  = (NE + B - 1) / B;          // 2344
  const int gELT = (NN * H + B - 1) / B;      // 25000
  const int gVN  = (NG * H + B - 1) / B;      // 256

  // ---- graph preprocessing ----
  k_fill_int<<<gNN, B, 0, stream>>>(deg, 1, NN);       // self-loop counts as 1
  k_fill_int<<<gNN, B, 0, stream>>>(cursor, 0, NN);
  k_fill_int<<<2, B, 0, stream>>>(gcnt, 0, NG);
  k_hist_edges<<<gNE, B, 0, stream>>>(e_dst, deg);
  k_hist_batch<<<gNN, B, 0, stream>>>(batch, gcnt);
  k_dinv<<<gNN, B, 0, stream>>>(deg, dinv);
  k_scan<<<1, 1024, 0, stream>>>(deg, rowptr);
  k_fill_csr<<<gNE, B, 0, stream>>>(e_src, e_dst, dinv, rowptr, cursor, csr_src, csr_norm);
  k_vn_init<<<gVN, B, 0, stream>>>(vn_emb, vn);

  const int mmGrid = (NN + 31) / 32;  // 1563

  // ---- conv layers 0,1 with virtual node MLP ----
  const float* cur = x;
  for (int i = 0; i < 2; i++) {
    int j = (i == 0) ? 1 : 0;  // torch negative-index wraparound
    // prop
    k_prop<<<NN, H, 0, stream>>>(cur, nullptr, hB, rowptr, csr_src, csr_norm, dinv, 1.f, 0.f);
    // matmul + bias
    k_mm_node<<<mmGrid, 256, 0, stream>>>(hB, W + (size_t)i * H * H, b + i * H, hC, NN);
    // BN stats
    k_zero_f<<<2, B, 0, stream>>>(stats, 512);
    k_colstats<<<256, H, 0, stream>>>(hC, NN, H, stats);
    // vt = vn (then atomically += h rows)
    k_copy_f<<<gVN, B, 0, stream>>>(vt, vn, NG * H);
    // bn+relu+vn add, scatter into vt
    k_bn_vn<<<gELT, B, 0, stream>>>(hC, stats, gamma + i * H, beta + i * H, vn, batch, hA, vt);
    // MLP on virtual node: t1 = relu(bn(vt@W1[j]+b1[j]))
    k_mm_small<<<(NG * 256 + B - 1) / B, B, 0, stream>>>(vt, W1 + (size_t)j * H * 256, b1 + j * 256, t1, NG, H, 256);
    k_zero_f<<<2, B, 0, stream>>>(stats, 512);
    k_colstats<<<16, 256, 0, stream>>>(t1, NG, 256, stats);
    k_bn_small<<<(NG * 256 + B - 1) / B, B, 0, stream>>>(t1, stats, g1 + j * 256, bt1 + j * 256, NG, 256);
    // t2 = relu(bn(t1@W2[j]+b2[j]))
    k_mm_small<<<(NG * H + B - 1) / B, B, 0, stream>>>(t1, W2 + (size_t)j * 256 * H, b2 + j * H, t2, NG, 256, H);
    k_zero_f<<<2, B, 0, stream>>>(stats, 512);
    k_colstats<<<16, H, 0, stream>>>(t2, NG, H, stats);
    k_bn_small<<<(NG * H + B - 1) / B, B, 0, stream>>>(t2, stats, g2 + j * H, bt2 + j * H, NG, H);
    // vn += t2
    k_add_f<<<gVN, B, 0, stream>>>(vn, t2, NG * H);
    cur = hA;
  }

  // ---- last conv layer: prop, matmul, BN (no relu) ----
  k_prop<<<NN, H, 0, stream>>>(hA, nullptr, hB, rowptr, csr_src, csr_norm, dinv, 1.f, 0.f);
  k_mm_node<<<mmGrid, 256, 0, stream>>>(hB, W + (size_t)2 * H * H, b + 2 * H, hC, NN);
  k_zero_f<<<2, B, 0, stream>>>(stats, 512);
  k_colstats<<<256, H, 0, stream>>>(hC, NN, H, stats);
  k_bn_plain<<<gELT, B, 0, stream>>>(hC, stats, gamma + 2 * H, beta + 2 * H, hA);

  // ---- APPNP: h0 = hA; 5 iterations ping-pong hB/hC ----
  k_prop<<<NN, H, 0, stream>>>(hA, hA, hB, rowptr, csr_src, csr_norm, dinv, 0.2f, 0.8f);
  k_prop<<<NN, H, 0, stream>>>(hB, hA, hC, rowptr, csr_src, csr_norm, dinv, 0.2f, 0.8f);
  k_prop<<<NN, H, 0, stream>>>(hC, hA, hB, rowptr, csr_src, csr_norm, dinv, 0.2f, 0.8f);
  k_prop<<<NN, H, 0, stream>>>(hB, hA, hC, rowptr, csr_src, csr_norm, dinv, 0.2f, 0.8f);
  k_prop<<<NN, H, 0, stream>>>(hC, hA, hB, rowptr, csr_src, csr_norm, dinv, 0.2f, 0.8f);

  // ---- mean pool + head ----
  k_zero_f<<<gVN, B, 0, stream>>>(pooled, NG * H);
  k_pool<<<gELT, B, 0, stream>>>(hB, batch, pooled);
  k_head<<<(NG * OUTC + B - 1) / B, B, 0, stream>>>(pooled, gcnt, Wout, bout, out);
}

// Round 2
// 992.596 us; speedup vs baseline: 1.3568x; 1.3568x over previous
//
#include <hip/hip_runtime.h>
#include <cstddef>
#include <cstdint>

#define NN 50000
#define NE 600000
#define H 128
#define NG 512
#define OUTC 128
#define EPSV 1e-5f
#define NB1 196   // ceil(NN/256)

// ---------------- combined init ----------------
// deg=1, cursor=0, gcnt=0, stats[9*512]=0, vtsum0/1=0, pooled=0, vn=vn_emb
__global__ void k_init(int* deg, int* cursor, int* gcnt, float* stats,
                       float* vtsum0, float* vtsum1, float* pooled,
                       const float* __restrict__ vn_emb, float* vn) {
  int i = blockIdx.x * blockDim.x + threadIdx.x;
  if (i < NN) { deg[i] = 1; cursor[i] = 0; }
  if (i < NG) gcnt[i] = 0;
  if (i < 9 * 512) stats[i] = 0.f;
  if (i < NG * H) {
    vtsum0[i] = 0.f; vtsum1[i] = 0.f; pooled[i] = 0.f;
    vn[i] = vn_emb[i & (H - 1)];
  }
}

// ---------------- graph preprocessing ----------------
__global__ void k_hist_edges(const int* __restrict__ dst, int* deg) {
  int e = blockIdx.x * blockDim.x + threadIdx.x;
  if (e < NE) atomicAdd(&deg[dst[e]], 1);
}
__global__ void k_hist_batch(const int* __restrict__ batch, int* gcnt) {
  int n = blockIdx.x * blockDim.x + threadIdx.x;
  if (n < NN) atomicAdd(&gcnt[batch[n]], 1);
}
__global__ void k_dinv(const int* __restrict__ deg, float* dinv) {
  int i = blockIdx.x * blockDim.x + threadIdx.x;
  if (i < NN) dinv[i] = rsqrtf((float)deg[i]);
}
// three-phase coalesced scan of (deg[i]-1)
__global__ void k_scan1(const int* __restrict__ deg, int* bsum) {
  __shared__ int sh[256];
  int t = threadIdx.x;
  int i = blockIdx.x * 256 + t;
  sh[t] = (i < NN) ? deg[i] - 1 : 0;
  __syncthreads();
  for (int o = 128; o > 0; o >>= 1) {
    if (t < o) sh[t] += sh[t + o];
    __syncthreads();
  }
  if (t == 0) bsum[blockIdx.x] = sh[0];
}
__global__ void k_scan2(const int* __restrict__ bsum, int* boff) {
  __shared__ int sh[256];
  int t = threadIdx.x;
  int v = (t < NB1) ? bsum[t] : 0;
  sh[t] = v;
  __syncthreads();
  for (int o = 1; o < 256; o <<= 1) {
    int u = (t >= o) ? sh[t - o] : 0;
    __syncthreads();
    sh[t] += u;
    __syncthreads();
  }
  if (t < NB1) boff[t] = sh[t] - v;
}
__global__ void k_scan3(const int* __restrict__ deg, const int* __restrict__ boff,
                        int* __restrict__ rowptr) {
  __shared__ int sh[256];
  int t = threadIdx.x;
  int i = blockIdx.x * 256 + t;
  int v = (i < NN) ? deg[i] - 1 : 0;
  sh[t] = v;
  __syncthreads();
  for (int o = 1; o < 256; o <<= 1) {
    int u = (t >= o) ? sh[t - o] : 0;
    __syncthreads();
    sh[t] += u;
    __syncthreads();
  }
  if (i < NN) rowptr[i] = boff[blockIdx.x] + sh[t] - v;
  if (i == NN - 1) rowptr[NN] = boff[blockIdx.x] + sh[t];
}
__global__ void k_fill_csr(const int* __restrict__ src, const int* __restrict__ dst,
                           const float* __restrict__ dinv, const int* __restrict__ rowptr,
                           int* cursor, int* __restrict__ csr_src, float* __restrict__ csr_norm) {
  int e = blockIdx.x * blockDim.x + threadIdx.x;
  if (e >= NE) return;
  int s = src[e], d = dst[e];
  int pos = rowptr[d] + atomicAdd(&cursor[d], 1);
  csr_src[pos] = s;
  csr_norm[pos] = dinv[s] * dinv[d];
}

// ---------------- propagation: out[d] = scale*(A_hat h)[d] + alpha*base[d] ----------------
// 8 rows per 256-thread block; 32 lanes x float4 per row.
__global__ __launch_bounds__(256) void k_prop(const float* __restrict__ h,
    const float* __restrict__ base, float* __restrict__ out,
    const int* __restrict__ rowptr, const int* __restrict__ csr_src,
    const float* __restrict__ csr_norm, const float* __restrict__ dinv,
    float scale, float alpha) {
  int lane = threadIdx.x & 31;
  int d = blockIdx.x * 8 + (threadIdx.x >> 5);
  const float4* h4 = (const float4*)h;
  float dv = dinv[d];
  size_t drow = (size_t)d * 32 + lane;
  float4 v = h4[drow];
  float w = dv * dv;
  float4 acc = make_float4(w * v.x, w * v.y, w * v.z, w * v.w);
  int e = rowptr[d], e1 = rowptr[d + 1];
  for (; e + 3 < e1; e += 4) {
    int s0 = csr_src[e], s1 = csr_src[e + 1], s2 = csr_src[e + 2], s3 = csr_src[e + 3];
    float n0 = csr_norm[e], n1 = csr_norm[e + 1], n2 = csr_norm[e + 2], n3 = csr_norm[e + 3];
    float4 a = h4[(size_t)s0 * 32 + lane];
    float4 b = h4[(size_t)s1 * 32 + lane];
    float4 c = h4[(size_t)s2 * 32 + lane];
    float4 dd = h4[(size_t)s3 * 32 + lane];
    acc.x += n0 * a.x + n1 * b.x + n2 * c.x + n3 * dd.x;
    acc.y += n0 * a.y + n1 * b.y + n2 * c.y + n3 * dd.y;
    acc.z += n0 * a.z + n1 * b.z + n2 * c.z + n3 * dd.z;
    acc.w += n0 * a.w + n1 * b.w + n2 * c.w + n3 * dd.w;
  }
  for (; e < e1; e++) {
    int s = csr_src[e];
    float nn = csr_norm[e];
    float4 a = h4[(size_t)s * 32 + lane];
    acc.x += nn * a.x; acc.y += nn * a.y; acc.z += nn * a.z; acc.w += nn * a.w;
  }
  float4 r = make_float4(scale * acc.x, scale * acc.y, scale * acc.z, scale * acc.w);
  if (base) {
    float4 bb = ((const float4*)base)[drow];
    r.x += alpha * bb.x; r.y += alpha * bb.y; r.z += alpha * bb.z; r.w += alpha * bb.w;
  }
  ((float4*)out)[drow] = r;
}

// ---------------- node-level matmul: Y[nrows x 128] = X @ W + bias ----------------
__global__ __launch_bounds__(256) void k_mm_node(const float* __restrict__ X,
    const float* __restrict__ Wg, const float* __restrict__ bias,
    float* __restrict__ Y, int nrows) {
  __shared__ float Wl[64 * H];
  __shared__ float Xl[32 * 64];
  int t = threadIdx.x;
  int rbase = blockIdx.x * 32;
  int cg = t & 15, rg = t >> 4;
  int c0 = cg * 8, r0 = rg * 2;
  float acc[2][8];
#pragma unroll
  for (int j = 0; j < 8; j++) { float bb = bias[c0 + j]; acc[0][j] = bb; acc[1][j] = bb; }
  for (int kt = 0; kt < 2; kt++) {
    __syncthreads();
    {
      const float4* Wv = (const float4*)Wg;
      float4* Wlv = (float4*)Wl;
#pragma unroll
      for (int i = 0; i < 8; i++) {
        int idx = t + i * 256;
        Wlv[idx] = Wv[kt * 2048 + idx];
      }
    }
    {
      float4* Xlv = (float4*)Xl;
#pragma unroll
      for (int i = 0; i < 2; i++) {
        int idx = t + i * 256;
        int r = idx >> 4, q = idx & 15;
        float4 v = make_float4(0.f, 0.f, 0.f, 0.f);
        int gr = rbase + r;
        if (gr < nrows) v = ((const float4*)X)[(size_t)gr * 32 + kt * 16 + q];
        Xlv[idx] = v;
      }
    }
    __syncthreads();
#pragma unroll 8
    for (int k = 0; k < 64; k++) {
      float x0 = Xl[r0 * 64 + k];
      float x1 = Xl[(r0 + 1) * 64 + k];
      float4 w0 = ((const float4*)Wl)[k * 32 + (c0 >> 2)];
      float4 w1 = ((const float4*)Wl)[k * 32 + (c0 >> 2) + 1];
      float w[8] = {w0.x, w0.y, w0.z, w0.w, w1.x, w1.y, w1.z, w1.w};
#pragma unroll
      for (int j = 0; j < 8; j++) { acc[0][j] += x0 * w[j]; acc[1][j] += x1 * w[j]; }
    }
  }
#pragma unroll
  for (int rr = 0; rr < 2; rr++) {
    int gr = rbase + r0 + rr;
    if (gr < nrows) {
      float4* dst = (float4*)&Y[(size_t)gr * H + c0];
      dst[0] = make_float4(acc[rr][0], acc[rr][1], acc[rr][2], acc[rr][3]);
      dst[1] = make_float4(acc[rr][4], acc[rr][5], acc[rr][6], acc[rr][7]);
    }
  }
}

// ---------------- column stats (sum, sumsq) ----------------
__global__ void k_colstats(const float* __restrict__ X, int nrows, int ncols, float* stats) {
  int c = threadIdx.x;
  int rows_per = (nrows + gridDim.x - 1) / gridDim.x;
  int r0 = blockIdx.x * rows_per;
  int r1 = r0 + rows_per; if (r1 > nrows) r1 = nrows;
  float s = 0.f, ss = 0.f;
  for (int r = r0; r < r1; r++) {
    float v = X[(size_t)r * ncols + c];
    s += v; ss += v * v;
  }
  atomicAdd(&stats[c], s);
  atomicAdd(&stats[ncols + c], ss);
}

// ---------------- BN+relu+vn add + segmented vt scatter (batch sorted) ----------------
__global__ void k_bn_vn2(const float* __restrict__ X, const float* __restrict__ stats,
                         const float* __restrict__ g, const float* __restrict__ bt,
                         const float* __restrict__ vn, const int* __restrict__ batch,
                         float* __restrict__ out, float* __restrict__ vtsum) {
  int c = threadIdx.x;                 // 128 threads
  int r0 = blockIdx.x * 32;
  int r1 = r0 + 32; if (r1 > NN) r1 = NN;
  const float invN = 1.0f / NN;
  float m = stats[c] * invN;
  float var = stats[H + c] * invN - m * m;
  float rs = rsqrtf(var + EPSV);
  float gc = g[c], bc = bt[c];
  int curb = batch[r0];
  float vnv = vn[curb * H + c];
  float s = 0.f;
  for (int r = r0; r < r1; r++) {
    int b = batch[r];
    if (b != curb) {
      atomicAdd(&vtsum[curb * H + c], s);
      s = 0.f; curb = b; vnv = vn[b * H + c];
    }
    float y = fmaxf(gc * (X[(size_t)r * H + c] - m) * rs + bc, 0.f) + vnv;
    out[(size_t)r * H + c] = y;
    s += y;
  }
  atomicAdd(&vtsum[curb * H + c], s);
}
// BN only (last conv layer)
__global__ void k_bn_plain(const float* __restrict__ X, const float* __restrict__ stats,
                           const float* __restrict__ g, const float* __restrict__ bt,
                           float* __restrict__ out) {
  int idx = blockIdx.x * blockDim.x + threadIdx.x;
  if (idx >= NN * H) return;
  int c = idx & (H - 1);
  const float invN = 1.0f / NN;
  float m = stats[c] * invN;
  float var = stats[H + c] * invN - m * m;
  float rs = rsqrtf(var + EPSV);
  out[idx] = g[c] * (X[idx] - m) * rs + bt[c];
}
// BN+relu in place, [NG x C]
__global__ void k_bn_small(float* Y, const float* __restrict__ stats,
                           const float* __restrict__ g, const float* __restrict__ bt,
                           int C) {
  int idx = blockIdx.x * blockDim.x + threadIdx.x;
  if (idx >= NG * 256 && C == 256) return;
  if (idx >= NG * C) return;
  int c = idx % C;
  const float invN = 1.0f / NG;
  float m = stats[c] * invN;
  float var = stats[C + c] * invN - m * m;
  float rs = rsqrtf(var + EPSV);
  Y[idx] = fmaxf(g[c] * (Y[idx] - m) * rs + bt[c], 0.f);
}
// BN+relu then vn += result, [NG x 128]
__global__ void k_bn_addvn(const float* __restrict__ Y, const float* __restrict__ stats,
                           const float* __restrict__ g, const float* __restrict__ bt,
                           float* vn) {
  int idx = blockIdx.x * blockDim.x + threadIdx.x;
  if (idx >= NG * H) return;
  int c = idx & (H - 1);
  const float invN = 1.0f / NG;
  float m = stats[c] * invN;
  float var = stats[H + c] * invN - m * m;
  float rs = rsqrtf(var + EPSV);
  vn[idx] += fmaxf(g[c] * (Y[idx] - m) * rs + bt[c], 0.f);
}

// ---------------- unrolled small matmuls ----------------
// t1[r, 0..255] = (vtsum[r]+vn[r]) @ W1 + b1 ; one block per row, 256 threads
__global__ void k_mm_vn1(const float* __restrict__ vtsum, const float* __restrict__ vn,
                         const float* __restrict__ W, const float* __restrict__ bias,
                         float* __restrict__ Y) {
  __shared__ float xs[H];
  int r = blockIdx.x, c = threadIdx.x;
  if (c < H) xs[c] = vtsum[r * H + c] + vn[r * H + c];
  __syncthreads();
  float acc = bias[c];
#pragma unroll 16
  for (int k = 0; k < H; k++) acc += xs[k] * W[k * 256 + c];
  Y[r * 256 + c] = acc;
}
// t2[r, 0..127] = t1[r] @ W2 + b2 ; one block per row, 128 threads
__global__ void k_mm_vn2(const float* __restrict__ X, const float* __restrict__ W,
                         const float* __restrict__ bias, float* __restrict__ Y) {
  __shared__ float xs[256];
  int r = blockIdx.x, c = threadIdx.x;
  xs[c] = X[r * 256 + c];
  xs[c + 128] = X[r * 256 + c + 128];
  __syncthreads();
  float acc = bias[c];
#pragma unroll 16
  for (int k = 0; k < 256; k++) acc += xs[k] * W[k * H + c];
  Y[r * H + c] = acc;
}

// ---------------- segmented pooling (batch sorted) ----------------
__global__ void k_pool2(const float* __restrict__ h, const int* __restrict__ batch,
                        float* pooled) {
  int c = threadIdx.x;                 // 128
  int r0 = blockIdx.x * 32;
  int r1 = r0 + 32; if (r1 > NN) r1 = NN;
  int curb = batch[r0];
  float s = 0.f;
  for (int r = r0; r < r1; r++) {
    int b = batch[r];
    if (b != curb) { atomicAdd(&pooled[curb * H + c], s); s = 0.f; curb = b; }
    s += h[(size_t)r * H + c];
  }
  atomicAdd(&pooled[curb * H + c], s);
}
__global__ void k_head(const float* __restrict__ pooled, const int* __restrict__ gcnt,
                       const float* __restrict__ Wout, const float* __restrict__ bout,
                       float* __restrict__ out) {
  __shared__ float xs[H];
  int r = blockIdx.x, c = threadIdx.x;
  float inv = 1.0f / fmaxf((float)gcnt[r], 1.0f);
  if (c < H) xs[c] = pooled[r * H + c] * inv;
  __syncthreads();
  float acc = bout[c];
#pragma unroll 16
  for (int k = 0; k < H; k++) acc += xs[k] * Wout[k * OUTC + c];
  out[r * OUTC + c] = acc;
}

// ---------------- launch ----------------
extern "C" void kernel_launch(void* const* d_in, const int* in_sizes, int n_in,
                              void* d_out, int out_size, void* d_ws, size_t ws_size,
                              hipStream_t stream) {
  const float* x      = (const float*)d_in[0];
  const int*   ei     = (const int*)d_in[1];
  const int*   e_src  = ei;
  const int*   e_dst  = ei + NE;
  const int*   batch  = (const int*)d_in[2];
  const float* W      = (const float*)d_in[3];
  const float* b      = (const float*)d_in[4];
  const float* gamma  = (const float*)d_in[5];
  const float* beta   = (const float*)d_in[6];
  const float* vn_emb = (const float*)d_in[7];
  const float* W1     = (const float*)d_in[8];
  const float* b1     = (const float*)d_in[9];
  const float* g1     = (const float*)d_in[10];
  const float* bt1    = (const float*)d_in[11];
  const float* W2     = (const float*)d_in[12];
  const float* b2     = (const float*)d_in[13];
  const float* g2     = (const float*)d_in[14];
  const float* bt2    = (const float*)d_in[15];
  const float* Wout   = (const float*)d_in[16];
  const float* bout   = (const float*)d_in[17];
  float* out = (float*)d_out;

  char* p = (char*)d_ws;
  auto alloc = [&](size_t bytes) -> char* {
    char* r = p; p += (bytes + 255) & ~(size_t)255; return r;
  };
  float* hA       = (float*)alloc((size_t)NN * H * 4);
  float* hB       = (float*)alloc((size_t)NN * H * 4);
  float* hC       = (float*)alloc((size_t)NN * H * 4);
  int*   deg      = (int*)alloc((size_t)NN * 4);
  int*   cursor   = (int*)alloc((size_t)NN * 4);
  int*   rowptr   = (int*)alloc((size_t)(NN + 1) * 4);
  int*   gcnt     = (int*)alloc(512 * 4);
  int*   csr_src  = (int*)alloc((size_t)NE * 4);
  float* csr_norm = (float*)alloc((size_t)NE * 4);
  float* dinv     = (float*)alloc((size_t)NN * 4);
  float* vn       = (float*)alloc((size_t)NG * H * 4);
  float* vtsum0   = (float*)alloc((size_t)NG * H * 4);
  float* vtsum1   = (float*)alloc((size_t)NG * H * 4);
  float* t1       = (float*)alloc((size_t)NG * 256 * 4);
  float* t2       = (float*)alloc((size_t)NG * H * 4);
  float* pooled   = (float*)alloc((size_t)NG * H * 4);
  float* stats    = (float*)alloc(9 * 512 * 4);
  int*   bsum     = (int*)alloc(256 * 4);
  int*   boff     = (int*)alloc(256 * 4);

  const int B = 256;
  const int gNN   = (NN + B - 1) / B;          // 196
  const int gNE   = (NE + B - 1) / B;
  const int gELT  = (NN * H + B - 1) / B;
  const int gVN   = (NG * H + B - 1) / B;      // 256
  const int gSEG  = (NN + 31) / 32;            // 1563
  const int gPROP = NN / 8;                    // 6250
  const int mmGrid = (NN + 31) / 32;

  // ---- init + graph preprocessing ----
  k_init<<<(NG * H + B - 1) / B, B, 0, stream>>>(deg, cursor, gcnt, stats, vtsum0, vtsum1,
                                                 pooled, vn_emb, vn);
  k_hist_edges<<<gNE, B, 0, stream>>>(e_dst, deg);
  k_hist_batch<<<gNN, B, 0, stream>>>(batch, gcnt);
  k_dinv<<<gNN, B, 0, stream>>>(deg, dinv);
  k_scan1<<<NB1, 256, 0, stream>>>(deg, bsum);
  k_scan2<<<1, 256, 0, stream>>>(bsum, boff);
  k_scan3<<<NB1, 256, 0, stream>>>(deg, boff, rowptr);
  k_fill_csr<<<gNE, B, 0, stream>>>(e_src, e_dst, dinv, rowptr, cursor, csr_src, csr_norm);

  // stats slots: 0:L0conv 1:L0t1 2:L0t2 3:L1conv 4:L1t1 5:L1t2 6:L2conv
  float* st[7];
  for (int i = 0; i < 7; i++) st[i] = stats + i * 512;

  // ---- conv layers 0,1 with virtual node MLP ----
  const float* cur = x;
  float* vts[2] = {vtsum0, vtsum1};
  for (int i = 0; i < 2; i++) {
    int j = (i == 0) ? 1 : 0;
    k_prop<<<gPROP, 256, 0, stream>>>(cur, nullptr, hB, rowptr, csr_src, csr_norm, dinv, 1.f, 0.f);
    k_mm_node<<<mmGrid, 256, 0, stream>>>(hB, W + (size_t)i * H * H, b + i * H, hC, NN);
    k_colstats<<<256, H, 0, stream>>>(hC, NN, H, st[3 * i]);
    k_bn_vn2<<<gSEG, H, 0, stream>>>(hC, st[3 * i], gamma + i * H, beta + i * H, vn, batch, hA, vts[i]);
    k_mm_vn1<<<NG, 256, 0, stream>>>(vts[i], vn, W1 + (size_t)j * H * 256, b1 + j * 256, t1);
    k_colstats<<<16, 256, 0, stream>>>(t1, NG, 256, st[3 * i + 1]);
    k_bn_small<<<(NG * 256 + B - 1) / B, B, 0, stream>>>(t1, st[3 * i + 1], g1 + j * 256, bt1 + j * 256, 256);
    k_mm_vn2<<<NG, 128, 0, stream>>>(t1, W2 + (size_t)j * 256 * H, b2 + j * H, t2);
    k_colstats<<<16, H, 0, stream>>>(t2, NG, H, st[3 * i + 2]);
    k_bn_addvn<<<gVN, B, 0, stream>>>(t2, st[3 * i + 2], g2 + j * H, bt2 + j * H, vn);
    cur = hA;
  }

  // ---- last conv layer ----
  k_prop<<<gPROP, 256, 0, stream>>>(hA, nullptr, hB, rowptr, csr_src, csr_norm, dinv, 1.f, 0.f);
  k_mm_node<<<mmGrid, 256, 0, stream>>>(hB, W + (size_t)2 * H * H, b + 2 * H, hC, NN);
  k_colstats<<<256, H, 0, stream>>>(hC, NN, H, st[6]);
  k_bn_plain<<<gELT, B, 0, stream>>>(hC, st[6], gamma + 2 * H, beta + 2 * H, hA);

  // ---- APPNP ----
  k_prop<<<gPROP, 256, 0, stream>>>(hA, hA, hB, rowptr, csr_src, csr_norm, dinv, 0.2f, 0.8f);
  k_prop<<<gPROP, 256, 0, stream>>>(hB, hA, hC, rowptr, csr_src, csr_norm, dinv, 0.2f, 0.8f);
  k_prop<<<gPROP, 256, 0, stream>>>(hC, hA, hB, rowptr, csr_src, csr_norm, dinv, 0.2f, 0.8f);
  k_prop<<<gPROP, 256, 0, stream>>>(hB, hA, hC, rowptr, csr_src, csr_norm, dinv, 0.2f, 0.8f);
  k_prop<<<gPROP, 256, 0, stream>>>(hC, hA, hB, rowptr, csr_src, csr_norm, dinv, 0.2f, 0.8f);

  // ---- mean pool + head ----
  k_pool2<<<gSEG, H, 0, stream>>>(hB, batch, pooled);
  k_head<<<NG, OUTC, 0, stream>>>(pooled, gcnt, Wout, bout, out);
}

// Round 3
// 972.468 us; speedup vs baseline: 1.3849x; 1.0207x over previous
//
#include <hip/hip_runtime.h>
#include <cstddef>
#include <cstdint>

#define NN 50000
#define NE 600000
#define H 128
#define NG 512
#define OUTC 128
#define EPSV 1e-5f
#define NB1 196   // ceil(NN/256)

// ---------------- combined init ----------------
__global__ void k_init(int* deg, int* cursor, int* gcnt, float* stats,
                       float* vtsum0, float* vtsum1, float* pooled,
                       const float* __restrict__ vn_emb, float* vn) {
  int i = blockIdx.x * blockDim.x + threadIdx.x;
  if (i < NN) { deg[i] = 1; cursor[i] = 0; }
  if (i < NG) gcnt[i] = 0;
  if (i < 9 * 512) stats[i] = 0.f;
  if (i < NG * H) {
    vtsum0[i] = 0.f; vtsum1[i] = 0.f; pooled[i] = 0.f;
    vn[i] = vn_emb[i & (H - 1)];
  }
}

// ---------------- graph preprocessing ----------------
__global__ void k_hist_edges(const int* __restrict__ dst, int* deg) {
  int e = blockIdx.x * blockDim.x + threadIdx.x;
  if (e < NE) atomicAdd(&deg[dst[e]], 1);
}
__global__ void k_hist_batch(const int* __restrict__ batch, int* gcnt) {
  int n = blockIdx.x * blockDim.x + threadIdx.x;
  if (n < NN) atomicAdd(&gcnt[batch[n]], 1);
}
__global__ void k_dinv(const int* __restrict__ deg, float* dinv) {
  int i = blockIdx.x * blockDim.x + threadIdx.x;
  if (i < NN) dinv[i] = rsqrtf((float)deg[i]);
}
__global__ void k_scan1(const int* __restrict__ deg, int* bsum) {
  __shared__ int sh[256];
  int t = threadIdx.x;
  int i = blockIdx.x * 256 + t;
  sh[t] = (i < NN) ? deg[i] - 1 : 0;
  __syncthreads();
  for (int o = 128; o > 0; o >>= 1) {
    if (t < o) sh[t] += sh[t + o];
    __syncthreads();
  }
  if (t == 0) bsum[blockIdx.x] = sh[0];
}
__global__ void k_scan2(const int* __restrict__ bsum, int* boff) {
  __shared__ int sh[256];
  int t = threadIdx.x;
  int v = (t < NB1) ? bsum[t] : 0;
  sh[t] = v;
  __syncthreads();
  for (int o = 1; o < 256; o <<= 1) {
    int u = (t >= o) ? sh[t - o] : 0;
    __syncthreads();
    sh[t] += u;
    __syncthreads();
  }
  if (t < NB1) boff[t] = sh[t] - v;
}
__global__ void k_scan3(const int* __restrict__ deg, const int* __restrict__ boff,
                        int* __restrict__ rowptr) {
  __shared__ int sh[256];
  int t = threadIdx.x;
  int i = blockIdx.x * 256 + t;
  int v = (i < NN) ? deg[i] - 1 : 0;
  sh[t] = v;
  __syncthreads();
  for (int o = 1; o < 256; o <<= 1) {
    int u = (t >= o) ? sh[t - o] : 0;
    __syncthreads();
    sh[t] += u;
    __syncthreads();
  }
  if (i < NN) rowptr[i] = boff[blockIdx.x] + sh[t] - v;
  if (i == NN - 1) rowptr[NN] = boff[blockIdx.x] + sh[t];
}
__global__ void k_fill_csr(const int* __restrict__ src, const int* __restrict__ dst,
                           const float* __restrict__ dinv, const int* __restrict__ rowptr,
                           int* cursor, int* __restrict__ csr_src, float* __restrict__ csr_norm) {
  int e = blockIdx.x * blockDim.x + threadIdx.x;
  if (e >= NE) return;
  int s = src[e], d = dst[e];
  int pos = rowptr[d] + atomicAdd(&cursor[d], 1);
  csr_src[pos] = s;
  csr_norm[pos] = dinv[s] * dinv[d];
}

// ---------------- propagation: out[d] = scale*(A_hat h)[d] + alpha*base[d] ----------------
// 8 rows per 256-thread block; 32 lanes x float4 per row; edge loop unrolled x8.
__global__ __launch_bounds__(256) void k_prop(const float* __restrict__ h,
    const float* __restrict__ base, float* __restrict__ out,
    const int* __restrict__ rowptr, const int* __restrict__ csr_src,
    const float* __restrict__ csr_norm, const float* __restrict__ dinv,
    float scale, float alpha) {
  int lane = threadIdx.x & 31;
  int d = blockIdx.x * 8 + (threadIdx.x >> 5);
  const float4* h4 = (const float4*)h;
  float dv = dinv[d];
  size_t drow = (size_t)d * 32 + lane;
  float4 v = h4[drow];
  float w = dv * dv;
  float4 acc = make_float4(w * v.x, w * v.y, w * v.z, w * v.w);
  int e = rowptr[d], e1 = rowptr[d + 1];
  for (; e + 7 < e1; e += 8) {
    int   si[8]; float nm[8]; float4 g[8];
#pragma unroll
    for (int u = 0; u < 8; u++) { si[u] = csr_src[e + u]; nm[u] = csr_norm[e + u]; }
#pragma unroll
    for (int u = 0; u < 8; u++) g[u] = h4[(size_t)si[u] * 32 + lane];
#pragma unroll
    for (int u = 0; u < 8; u++) {
      acc.x += nm[u] * g[u].x; acc.y += nm[u] * g[u].y;
      acc.z += nm[u] * g[u].z; acc.w += nm[u] * g[u].w;
    }
  }
  if (e + 3 < e1) {
    int   si[4]; float nm[4]; float4 g[4];
#pragma unroll
    for (int u = 0; u < 4; u++) { si[u] = csr_src[e + u]; nm[u] = csr_norm[e + u]; }
#pragma unroll
    for (int u = 0; u < 4; u++) g[u] = h4[(size_t)si[u] * 32 + lane];
#pragma unroll
    for (int u = 0; u < 4; u++) {
      acc.x += nm[u] * g[u].x; acc.y += nm[u] * g[u].y;
      acc.z += nm[u] * g[u].z; acc.w += nm[u] * g[u].w;
    }
    e += 4;
  }
  for (; e < e1; e++) {
    int s = csr_src[e];
    float nn = csr_norm[e];
    float4 a = h4[(size_t)s * 32 + lane];
    acc.x += nn * a.x; acc.y += nn * a.y; acc.z += nn * a.z; acc.w += nn * a.w;
  }
  float4 r = make_float4(scale * acc.x, scale * acc.y, scale * acc.z, scale * acc.w);
  if (base) {
    float4 bb = ((const float4*)base)[drow];
    r.x += alpha * bb.x; r.y += alpha * bb.y; r.z += alpha * bb.z; r.w += alpha * bb.w;
  }
  ((float4*)out)[drow] = r;
}

// ---------------- node-level matmul + fused column stats ----------------
// Y[nrows x 128] = X @ W + bias; also atomically accumulates column sum/sumsq
// of Y into gstats[0..127] / gstats[128..255].
__global__ __launch_bounds__(256) void k_mm_node(const float* __restrict__ X,
    const float* __restrict__ Wg, const float* __restrict__ bias,
    float* __restrict__ Y, int nrows, float* __restrict__ gstats) {
  __shared__ float Wl[64 * H];
  __shared__ float Xl[32 * 64];
  __shared__ float csum[H];
  __shared__ float csqs[H];
  int t = threadIdx.x;
  int rbase = blockIdx.x * 32;
  int cg = t & 15, rg = t >> 4;
  int c0 = cg * 8, r0 = rg * 2;
  float acc[2][8];
#pragma unroll
  for (int j = 0; j < 8; j++) { float bb = bias[c0 + j]; acc[0][j] = bb; acc[1][j] = bb; }
  if (t < H) { csum[t] = 0.f; csqs[t] = 0.f; }
  for (int kt = 0; kt < 2; kt++) {
    __syncthreads();
    {
      const float4* Wv = (const float4*)Wg;
      float4* Wlv = (float4*)Wl;
#pragma unroll
      for (int i = 0; i < 8; i++) {
        int idx = t + i * 256;
        Wlv[idx] = Wv[kt * 2048 + idx];
      }
    }
    {
      float4* Xlv = (float4*)Xl;
#pragma unroll
      for (int i = 0; i < 2; i++) {
        int idx = t + i * 256;
        int r = idx >> 4, q = idx & 15;
        float4 v = make_float4(0.f, 0.f, 0.f, 0.f);
        int gr = rbase + r;
        if (gr < nrows) v = ((const float4*)X)[(size_t)gr * 32 + kt * 16 + q];
        Xlv[idx] = v;
      }
    }
    __syncthreads();
#pragma unroll 8
    for (int k = 0; k < 64; k++) {
      float x0 = Xl[r0 * 64 + k];
      float x1 = Xl[(r0 + 1) * 64 + k];
      float4 w0 = ((const float4*)Wl)[k * 32 + (c0 >> 2)];
      float4 w1 = ((const float4*)Wl)[k * 32 + (c0 >> 2) + 1];
      float w[8] = {w0.x, w0.y, w0.z, w0.w, w1.x, w1.y, w1.z, w1.w};
#pragma unroll
      for (int j = 0; j < 8; j++) { acc[0][j] += x0 * w[j]; acc[1][j] += x1 * w[j]; }
    }
  }
  bool ok0 = (rbase + r0) < nrows;
  bool ok1 = (rbase + r0 + 1) < nrows;
#pragma unroll
  for (int rr = 0; rr < 2; rr++) {
    int gr = rbase + r0 + rr;
    if (gr < nrows) {
      float4* dst = (float4*)&Y[(size_t)gr * H + c0];
      dst[0] = make_float4(acc[rr][0], acc[rr][1], acc[rr][2], acc[rr][3]);
      dst[1] = make_float4(acc[rr][4], acc[rr][5], acc[rr][6], acc[rr][7]);
    }
  }
  // fused column stats over this block's (valid) rows
#pragma unroll
  for (int j = 0; j < 8; j++) {
    float a0 = ok0 ? acc[0][j] : 0.f;
    float a1 = ok1 ? acc[1][j] : 0.f;
    atomicAdd(&csum[c0 + j], a0 + a1);
    atomicAdd(&csqs[c0 + j], a0 * a0 + a1 * a1);
  }
  __syncthreads();
  if (t < H) {
    atomicAdd(&gstats[t], csum[t]);
    atomicAdd(&gstats[H + t], csqs[t]);
  }
}

// ---------------- BN+relu+vn add + segmented vt scatter (batch sorted) ----------------
__global__ void k_bn_vn2(const float* __restrict__ X, const float* __restrict__ stats,
                         const float* __restrict__ g, const float* __restrict__ bt,
                         const float* __restrict__ vn, const int* __restrict__ batch,
                         float* __restrict__ out, float* __restrict__ vtsum) {
  int c = threadIdx.x;
  int r0 = blockIdx.x * 32;
  int r1 = r0 + 32; if (r1 > NN) r1 = NN;
  const float invN = 1.0f / NN;
  float m = stats[c] * invN;
  float var = stats[H + c] * invN - m * m;
  float rs = rsqrtf(var + EPSV);
  float gc = g[c], bc = bt[c];
  int curb = batch[r0];
  float vnv = vn[curb * H + c];
  float s = 0.f;
  for (int r = r0; r < r1; r++) {
    int b = batch[r];
    if (b != curb) {
      atomicAdd(&vtsum[curb * H + c], s);
      s = 0.f; curb = b; vnv = vn[b * H + c];
    }
    float y = fmaxf(gc * (X[(size_t)r * H + c] - m) * rs + bc, 0.f) + vnv;
    out[(size_t)r * H + c] = y;
    s += y;
  }
  atomicAdd(&vtsum[curb * H + c], s);
}
// BN only (last conv layer)
__global__ void k_bn_plain(const float* __restrict__ X, const float* __restrict__ stats,
                           const float* __restrict__ g, const float* __restrict__ bt,
                           float* __restrict__ out) {
  int idx = blockIdx.x * blockDim.x + threadIdx.x;
  if (idx >= NN * H) return;
  int c = idx & (H - 1);
  const float invN = 1.0f / NN;
  float m = stats[c] * invN;
  float var = stats[H + c] * invN - m * m;
  float rs = rsqrtf(var + EPSV);
  out[idx] = g[c] * (X[idx] - m) * rs + bt[c];
}
// BN+relu in place, [NG x C]
__global__ void k_bn_small(float* Y, const float* __restrict__ stats,
                           const float* __restrict__ g, const float* __restrict__ bt,
                           int C) {
  int idx = blockIdx.x * blockDim.x + threadIdx.x;
  if (idx >= NG * C) return;
  int c = idx % C;
  const float invN = 1.0f / NG;
  float m = stats[c] * invN;
  float var = stats[C + c] * invN - m * m;
  float rs = rsqrtf(var + EPSV);
  Y[idx] = fmaxf(g[c] * (Y[idx] - m) * rs + bt[c], 0.f);
}
// BN+relu then vn += result, [NG x 128]
__global__ void k_bn_addvn(const float* __restrict__ Y, const float* __restrict__ stats,
                           const float* __restrict__ g, const float* __restrict__ bt,
                           float* vn) {
  int idx = blockIdx.x * blockDim.x + threadIdx.x;
  if (idx >= NG * H) return;
  int c = idx & (H - 1);
  const float invN = 1.0f / NG;
  float m = stats[c] * invN;
  float var = stats[H + c] * invN - m * m;
  float rs = rsqrtf(var + EPSV);
  vn[idx] += fmaxf(g[c] * (Y[idx] - m) * rs + bt[c], 0.f);
}

// ---------------- small matmuls with fused stats ----------------
// t1[r, 0..255] = (vtsum[r]+vn[r]) @ W1 + b1 ; one block per row; stats fused.
__global__ void k_mm_vn1(const float* __restrict__ vtsum, const float* __restrict__ vn,
                         const float* __restrict__ W, const float* __restrict__ bias,
                         float* __restrict__ Y, float* __restrict__ gstats) {
  __shared__ float xs[H];
  int r = blockIdx.x, c = threadIdx.x;
  if (c < H) xs[c] = vtsum[r * H + c] + vn[r * H + c];
  __syncthreads();
  float acc = bias[c];
#pragma unroll 16
  for (int k = 0; k < H; k++) acc += xs[k] * W[k * 256 + c];
  Y[r * 256 + c] = acc;
  atomicAdd(&gstats[c], acc);
  atomicAdd(&gstats[256 + c], acc * acc);
}
// t2[r, 0..127] = t1[r] @ W2 + b2 ; one block per row; stats fused.
__global__ void k_mm_vn2(const float* __restrict__ X, const float* __restrict__ W,
                         const float* __restrict__ bias, float* __restrict__ Y,
                         float* __restrict__ gstats) {
  __shared__ float xs[256];
  int r = blockIdx.x, c = threadIdx.x;
  xs[c] = X[r * 256 + c];
  xs[c + 128] = X[r * 256 + c + 128];
  __syncthreads();
  float acc = bias[c];
#pragma unroll 16
  for (int k = 0; k < 256; k++) acc += xs[k] * W[k * H + c];
  Y[r * H + c] = acc;
  atomicAdd(&gstats[c], acc);
  atomicAdd(&gstats[H + c], acc * acc);
}

// ---------------- segmented pooling (batch sorted) ----------------
__global__ void k_pool2(const float* __restrict__ h, const int* __restrict__ batch,
                        float* pooled) {
  int c = threadIdx.x;
  int r0 = blockIdx.x * 32;
  int r1 = r0 + 32; if (r1 > NN) r1 = NN;
  int curb = batch[r0];
  float s = 0.f;
  for (int r = r0; r < r1; r++) {
    int b = batch[r];
    if (b != curb) { atomicAdd(&pooled[curb * H + c], s); s = 0.f; curb = b; }
    s += h[(size_t)r * H + c];
  }
  atomicAdd(&pooled[curb * H + c], s);
}
__global__ void k_head(const float* __restrict__ pooled, const int* __restrict__ gcnt,
                       const float* __restrict__ Wout, const float* __restrict__ bout,
                       float* __restrict__ out) {
  __shared__ float xs[H];
  int r = blockIdx.x, c = threadIdx.x;
  float inv = 1.0f / fmaxf((float)gcnt[r], 1.0f);
  if (c < H) xs[c] = pooled[r * H + c] * inv;
  __syncthreads();
  float acc = bout[c];
#pragma unroll 16
  for (int k = 0; k < H; k++) acc += xs[k] * Wout[k * OUTC + c];
  out[r * OUTC + c] = acc;
}

// ---------------- launch ----------------
extern "C" void kernel_launch(void* const* d_in, const int* in_sizes, int n_in,
                              void* d_out, int out_size, void* d_ws, size_t ws_size,
                              hipStream_t stream) {
  const float* x      = (const float*)d_in[0];
  const int*   ei     = (const int*)d_in[1];
  const int*   e_src  = ei;
  const int*   e_dst  = ei + NE;
  const int*   batch  = (const int*)d_in[2];
  const float* W      = (const float*)d_in[3];
  const float* b      = (const float*)d_in[4];
  const float* gamma  = (const float*)d_in[5];
  const float* beta   = (const float*)d_in[6];
  const float* vn_emb = (const float*)d_in[7];
  const float* W1     = (const float*)d_in[8];
  const float* b1     = (const float*)d_in[9];
  const float* g1     = (const float*)d_in[10];
  const float* bt1    = (const float*)d_in[11];
  const float* W2     = (const float*)d_in[12];
  const float* b2     = (const float*)d_in[13];
  const float* g2     = (const float*)d_in[14];
  const float* bt2    = (const float*)d_in[15];
  const float* Wout   = (const float*)d_in[16];
  const float* bout   = (const float*)d_in[17];
  float* out = (float*)d_out;

  char* p = (char*)d_ws;
  auto alloc = [&](size_t bytes) -> char* {
    char* r = p; p += (bytes + 255) & ~(size_t)255; return r;
  };
  float* hA       = (float*)alloc((size_t)NN * H * 4);
  float* hB       = (float*)alloc((size_t)NN * H * 4);
  float* hC       = (float*)alloc((size_t)NN * H * 4);
  int*   deg      = (int*)alloc((size_t)NN * 4);
  int*   cursor   = (int*)alloc((size_t)NN * 4);
  int*   rowptr   = (int*)alloc((size_t)(NN + 1) * 4);
  int*   gcnt     = (int*)alloc(512 * 4);
  int*   csr_src  = (int*)alloc((size_t)NE * 4);
  float* csr_norm = (float*)alloc((size_t)NE * 4);
  float* dinv     = (float*)alloc((size_t)NN * 4);
  float* vn       = (float*)alloc((size_t)NG * H * 4);
  float* vtsum0   = (float*)alloc((size_t)NG * H * 4);
  float* vtsum1   = (float*)alloc((size_t)NG * H * 4);
  float* t1       = (float*)alloc((size_t)NG * 256 * 4);
  float* t2       = (float*)alloc((size_t)NG * H * 4);
  float* pooled   = (float*)alloc((size_t)NG * H * 4);
  float* stats    = (float*)alloc(9 * 512 * 4);
  int*   bsum     = (int*)alloc(256 * 4);
  int*   boff     = (int*)alloc(256 * 4);

  const int B = 256;
  const int gNN   = (NN + B - 1) / B;
  const int gNE   = (NE + B - 1) / B;
  const int gELT  = (NN * H + B - 1) / B;
  const int gVN   = (NG * H + B - 1) / B;
  const int gSEG  = (NN + 31) / 32;
  const int gPROP = NN / 8;
  const int mmGrid = (NN + 31) / 32;

  // ---- init + graph preprocessing ----
  k_init<<<(NG * H + B - 1) / B, B, 0, stream>>>(deg, cursor, gcnt, stats, vtsum0, vtsum1,
                                                 pooled, vn_emb, vn);
  k_hist_edges<<<gNE, B, 0, stream>>>(e_dst, deg);
  k_hist_batch<<<gNN, B, 0, stream>>>(batch, gcnt);
  k_dinv<<<gNN, B, 0, stream>>>(deg, dinv);
  k_scan1<<<NB1, 256, 0, stream>>>(deg, bsum);
  k_scan2<<<1, 256, 0, stream>>>(bsum, boff);
  k_scan3<<<NB1, 256, 0, stream>>>(deg, boff, rowptr);
  k_fill_csr<<<gNE, B, 0, stream>>>(e_src, e_dst, dinv, rowptr, cursor, csr_src, csr_norm);

  // stats slots: 0:L0conv 1:L0t1 2:L0t2 3:L1conv 4:L1t1 5:L1t2 6:L2conv
  float* st[7];
  for (int i = 0; i < 7; i++) st[i] = stats + i * 512;

  // ---- conv layers 0,1 with virtual node MLP ----
  const float* cur = x;
  float* vts[2] = {vtsum0, vtsum1};
  for (int i = 0; i < 2; i++) {
    int j = (i == 0) ? 1 : 0;
    k_prop<<<gPROP, 256, 0, stream>>>(cur, nullptr, hB, rowptr, csr_src, csr_norm, dinv, 1.f, 0.f);
    k_mm_node<<<mmGrid, 256, 0, stream>>>(hB, W + (size_t)i * H * H, b + i * H, hC, NN, st[3 * i]);
    k_bn_vn2<<<gSEG, H, 0, stream>>>(hC, st[3 * i], gamma + i * H, beta + i * H, vn, batch, hA, vts[i]);
    k_mm_vn1<<<NG, 256, 0, stream>>>(vts[i], vn, W1 + (size_t)j * H * 256, b1 + j * 256, t1, st[3 * i + 1]);
    k_bn_small<<<(NG * 256 + B - 1) / B, B, 0, stream>>>(t1, st[3 * i + 1], g1 + j * 256, bt1 + j * 256, 256);
    k_mm_vn2<<<NG, 128, 0, stream>>>(t1, W2 + (size_t)j * 256 * H, b2 + j * H, t2, st[3 * i + 2]);
    k_bn_addvn<<<gVN, B, 0, stream>>>(t2, st[3 * i + 2], g2 + j * H, bt2 + j * H, vn);
    cur = hA;
  }

  // ---- last conv layer ----
  k_prop<<<gPROP, 256, 0, stream>>>(hA, nullptr, hB, rowptr, csr_src, csr_norm, dinv, 1.f, 0.f);
  k_mm_node<<<mmGrid, 256, 0, stream>>>(hB, W + (size_t)2 * H * H, b + 2 * H, hC, NN, st[6]);
  k_bn_plain<<<gELT, B, 0, stream>>>(hC, st[6], gamma + 2 * H, beta + 2 * H, hA);

  // ---- APPNP ----
  k_prop<<<gPROP, 256, 0, stream>>>(hA, hA, hB, rowptr, csr_src, csr_norm, dinv, 0.2f, 0.8f);
  k_prop<<<gPROP, 256, 0, stream>>>(hB, hA, hC, rowptr, csr_src, csr_norm, dinv, 0.2f, 0.8f);
  k_prop<<<gPROP, 256, 0, stream>>>(hC, hA, hB, rowptr, csr_src, csr_norm, dinv, 0.2f, 0.8f);
  k_prop<<<gPROP, 256, 0, stream>>>(hB, hA, hC, rowptr, csr_src, csr_norm, dinv, 0.2f, 0.8f);
  k_prop<<<gPROP, 256, 0, stream>>>(hC, hA, hB, rowptr, csr_src, csr_norm, dinv, 0.2f, 0.8f);

  // ---- mean pool + head ----
  k_pool2<<<gSEG, H, 0, stream>>>(hB, batch, pooled);
  k_head<<<NG, OUTC, 0, stream>>>(pooled, gcnt, Wout, bout, out);
}

// Round 4
// 778.638 us; speedup vs baseline: 1.7296x; 1.2489x over previous
//
#include <hip/hip_runtime.h>
#include <cstddef>
#include <cstdint>

#define NN 50000
#define NE 600000
#define H 128
#define NG 512
#define OUTC 128
#define EPSV 1e-5f
#define NB1 196   // ceil(NN/256)

__device__ __forceinline__ unsigned short f2b(float f) {
  uint32_t u = __float_as_uint(f);
  uint32_t r = u + 0x7FFFu + ((u >> 16) & 1u);
  return (unsigned short)(r >> 16);
}
__device__ __forceinline__ float4 b4_to_f4(uint2 v) {
  float4 f;
  f.x = __uint_as_float(v.x << 16);
  f.y = __uint_as_float(v.x & 0xFFFF0000u);
  f.z = __uint_as_float(v.y << 16);
  f.w = __uint_as_float(v.y & 0xFFFF0000u);
  return f;
}

// ---------------- combined init ----------------
__global__ void k_init(int* deg, int* cursor, int* gcnt, float* stats,
                       float* vtsum0, float* vtsum1, float* pooled,
                       const float* __restrict__ vn_emb, float* vn) {
  int i = blockIdx.x * blockDim.x + threadIdx.x;
  if (i < NN) { deg[i] = 1; cursor[i] = 0; }
  if (i < NG) gcnt[i] = 0;
  if (i < 9 * 512) stats[i] = 0.f;
  if (i < NG * H) {
    vtsum0[i] = 0.f; vtsum1[i] = 0.f; pooled[i] = 0.f;
    vn[i] = vn_emb[i & (H - 1)];
  }
}

// ---------------- graph preprocessing ----------------
__global__ void k_hist_edges(const int* __restrict__ dst, int* deg) {
  int e = blockIdx.x * blockDim.x + threadIdx.x;
  if (e < NE) atomicAdd(&deg[dst[e]], 1);
}
__global__ void k_hist_batch(const int* __restrict__ batch, int* gcnt) {
  int n = blockIdx.x * blockDim.x + threadIdx.x;
  if (n < NN) atomicAdd(&gcnt[batch[n]], 1);
}
__global__ void k_dinv(const int* __restrict__ deg, float* dinv) {
  int i = blockIdx.x * blockDim.x + threadIdx.x;
  if (i < NN) dinv[i] = rsqrtf((float)deg[i]);
}
__global__ void k_scan1(const int* __restrict__ deg, int* bsum) {
  __shared__ int sh[256];
  int t = threadIdx.x;
  int i = blockIdx.x * 256 + t;
  sh[t] = (i < NN) ? deg[i] - 1 : 0;
  __syncthreads();
  for (int o = 128; o > 0; o >>= 1) {
    if (t < o) sh[t] += sh[t + o];
    __syncthreads();
  }
  if (t == 0) bsum[blockIdx.x] = sh[0];
}
__global__ void k_scan2(const int* __restrict__ bsum, int* boff) {
  __shared__ int sh[256];
  int t = threadIdx.x;
  int v = (t < NB1) ? bsum[t] : 0;
  sh[t] = v;
  __syncthreads();
  for (int o = 1; o < 256; o <<= 1) {
    int u = (t >= o) ? sh[t - o] : 0;
    __syncthreads();
    sh[t] += u;
    __syncthreads();
  }
  if (t < NB1) boff[t] = sh[t] - v;
}
__global__ void k_scan3(const int* __restrict__ deg, const int* __restrict__ boff,
                        int* __restrict__ rowptr) {
  __shared__ int sh[256];
  int t = threadIdx.x;
  int i = blockIdx.x * 256 + t;
  int v = (i < NN) ? deg[i] - 1 : 0;
  sh[t] = v;
  __syncthreads();
  for (int o = 1; o < 256; o <<= 1) {
    int u = (t >= o) ? sh[t - o] : 0;
    __syncthreads();
    sh[t] += u;
    __syncthreads();
  }
  if (i < NN) rowptr[i] = boff[blockIdx.x] + sh[t] - v;
  if (i == NN - 1) rowptr[NN] = boff[blockIdx.x] + sh[t];
}
__global__ void k_fill_csr(const int* __restrict__ src, const int* __restrict__ dst,
                           const float* __restrict__ dinv, const int* __restrict__ rowptr,
                           int* cursor, int* __restrict__ csr_src, float* __restrict__ csr_norm) {
  int e = blockIdx.x * blockDim.x + threadIdx.x;
  if (e >= NE) return;
  int s = src[e], d = dst[e];
  int pos = rowptr[d] + atomicAdd(&cursor[d], 1);
  csr_src[pos] = s;
  csr_norm[pos] = dinv[s] * dinv[d];
}

// ---------------- fp32 propagation (conv layers) ----------------
__global__ __launch_bounds__(256) void k_prop(const float* __restrict__ h,
    float* __restrict__ out,
    const int* __restrict__ rowptr, const int* __restrict__ csr_src,
    const float* __restrict__ csr_norm, const float* __restrict__ dinv) {
  int lane = threadIdx.x & 31;
  int d = blockIdx.x * 8 + (threadIdx.x >> 5);
  const float4* h4 = (const float4*)h;
  float dv = dinv[d];
  size_t drow = (size_t)d * 32 + lane;
  float4 v = h4[drow];
  float w = dv * dv;
  float4 acc = make_float4(w * v.x, w * v.y, w * v.z, w * v.w);
  int e = rowptr[d], e1 = rowptr[d + 1];
  for (; e + 7 < e1; e += 8) {
    int   si[8]; float nm[8]; float4 g[8];
#pragma unroll
    for (int u = 0; u < 8; u++) { si[u] = csr_src[e + u]; nm[u] = csr_norm[e + u]; }
#pragma unroll
    for (int u = 0; u < 8; u++) g[u] = h4[(size_t)si[u] * 32 + lane];
#pragma unroll
    for (int u = 0; u < 8; u++) {
      acc.x += nm[u] * g[u].x; acc.y += nm[u] * g[u].y;
      acc.z += nm[u] * g[u].z; acc.w += nm[u] * g[u].w;
    }
  }
  if (e + 3 < e1) {
    int   si[4]; float nm[4]; float4 g[4];
#pragma unroll
    for (int u = 0; u < 4; u++) { si[u] = csr_src[e + u]; nm[u] = csr_norm[e + u]; }
#pragma unroll
    for (int u = 0; u < 4; u++) g[u] = h4[(size_t)si[u] * 32 + lane];
#pragma unroll
    for (int u = 0; u < 4; u++) {
      acc.x += nm[u] * g[u].x; acc.y += nm[u] * g[u].y;
      acc.z += nm[u] * g[u].z; acc.w += nm[u] * g[u].w;
    }
    e += 4;
  }
  for (; e < e1; e++) {
    int s = csr_src[e];
    float nn = csr_norm[e];
    float4 a = h4[(size_t)s * 32 + lane];
    acc.x += nn * a.x; acc.y += nn * a.y; acc.z += nn * a.z; acc.w += nn * a.w;
  }
  ((float4*)out)[drow] = acc;
}

// ---------------- bf16-gather APPNP propagation ----------------
// out = 0.2 * (A_hat hb) + 0.8 * base; writes bf16 (outb) or fp32 (outf).
__global__ __launch_bounds__(256) void k_prop_b(const unsigned short* __restrict__ hb,
    const float* __restrict__ base, unsigned short* __restrict__ outb,
    float* __restrict__ outf,
    const int* __restrict__ rowptr, const int* __restrict__ csr_src,
    const float* __restrict__ csr_norm, const float* __restrict__ dinv) {
  int lane = threadIdx.x & 31;
  int d = blockIdx.x * 8 + (threadIdx.x >> 5);
  const uint2* h2 = (const uint2*)hb;
  float dv = dinv[d];
  size_t drow = (size_t)d * 32 + lane;
  float4 v = b4_to_f4(h2[drow]);
  float w = dv * dv;
  float4 acc = make_float4(w * v.x, w * v.y, w * v.z, w * v.w);
  int e = rowptr[d], e1 = rowptr[d + 1];
  for (; e + 7 < e1; e += 8) {
    int   si[8]; float nm[8]; uint2 g[8];
#pragma unroll
    for (int u = 0; u < 8; u++) { si[u] = csr_src[e + u]; nm[u] = csr_norm[e + u]; }
#pragma unroll
    for (int u = 0; u < 8; u++) g[u] = h2[(size_t)si[u] * 32 + lane];
#pragma unroll
    for (int u = 0; u < 8; u++) {
      float4 f = b4_to_f4(g[u]);
      acc.x += nm[u] * f.x; acc.y += nm[u] * f.y;
      acc.z += nm[u] * f.z; acc.w += nm[u] * f.w;
    }
  }
  if (e + 3 < e1) {
    int   si[4]; float nm[4]; uint2 g[4];
#pragma unroll
    for (int u = 0; u < 4; u++) { si[u] = csr_src[e + u]; nm[u] = csr_norm[e + u]; }
#pragma unroll
    for (int u = 0; u < 4; u++) g[u] = h2[(size_t)si[u] * 32 + lane];
#pragma unroll
    for (int u = 0; u < 4; u++) {
      float4 f = b4_to_f4(g[u]);
      acc.x += nm[u] * f.x; acc.y += nm[u] * f.y;
      acc.z += nm[u] * f.z; acc.w += nm[u] * f.w;
    }
    e += 4;
  }
  for (; e < e1; e++) {
    int s = csr_src[e];
    float nn = csr_norm[e];
    float4 f = b4_to_f4(h2[(size_t)s * 32 + lane]);
    acc.x += nn * f.x; acc.y += nn * f.y; acc.z += nn * f.z; acc.w += nn * f.w;
  }
  float4 bb = ((const float4*)base)[drow];
  float4 r;
  r.x = 0.2f * acc.x + 0.8f * bb.x;
  r.y = 0.2f * acc.y + 0.8f * bb.y;
  r.z = 0.2f * acc.z + 0.8f * bb.z;
  r.w = 0.2f * acc.w + 0.8f * bb.w;
  if (outb) {
    uint2 o;
    o.x = (uint32_t)f2b(r.x) | ((uint32_t)f2b(r.y) << 16);
    o.y = (uint32_t)f2b(r.z) | ((uint32_t)f2b(r.w) << 16);
    ((uint2*)outb)[drow] = o;
  } else {
    ((float4*)outf)[drow] = r;
  }
}

// ---------------- node-level matmul + fused column stats (shuffle reduce) ----------------
__global__ __launch_bounds__(256) void k_mm_node(const float* __restrict__ X,
    const float* __restrict__ Wg, const float* __restrict__ bias,
    float* __restrict__ Y, int nrows, float* __restrict__ gstats) {
  __shared__ float Wl[64 * H];
  __shared__ float Xl[32 * 64];
  __shared__ float wsum[4][H];
  __shared__ float wsq[4][H];
  int t = threadIdx.x;
  int rbase = blockIdx.x * 32;
  int cg = t & 15, rg = t >> 4;
  int c0 = cg * 8, r0 = rg * 2;
  float acc[2][8];
#pragma unroll
  for (int j = 0; j < 8; j++) { float bb = bias[c0 + j]; acc[0][j] = bb; acc[1][j] = bb; }
  for (int kt = 0; kt < 2; kt++) {
    __syncthreads();
    {
      const float4* Wv = (const float4*)Wg;
      float4* Wlv = (float4*)Wl;
#pragma unroll
      for (int i = 0; i < 8; i++) {
        int idx = t + i * 256;
        Wlv[idx] = Wv[kt * 2048 + idx];
      }
    }
    {
      float4* Xlv = (float4*)Xl;
#pragma unroll
      for (int i = 0; i < 2; i++) {
        int idx = t + i * 256;
        int r = idx >> 4, q = idx & 15;
        float4 v = make_float4(0.f, 0.f, 0.f, 0.f);
        int gr = rbase + r;
        if (gr < nrows) v = ((const float4*)X)[(size_t)gr * 32 + kt * 16 + q];
        Xlv[idx] = v;
      }
    }
    __syncthreads();
#pragma unroll 8
    for (int k = 0; k < 64; k++) {
      float x0 = Xl[r0 * 64 + k];
      float x1 = Xl[(r0 + 1) * 64 + k];
      float4 w0 = ((const float4*)Wl)[k * 32 + (c0 >> 2)];
      float4 w1 = ((const float4*)Wl)[k * 32 + (c0 >> 2) + 1];
      float w[8] = {w0.x, w0.y, w0.z, w0.w, w1.x, w1.y, w1.z, w1.w};
#pragma unroll
      for (int j = 0; j < 8; j++) { acc[0][j] += x0 * w[j]; acc[1][j] += x1 * w[j]; }
    }
  }
  bool ok0 = (rbase + r0) < nrows;
  bool ok1 = (rbase + r0 + 1) < nrows;
#pragma unroll
  for (int rr = 0; rr < 2; rr++) {
    int gr = rbase + r0 + rr;
    if (gr < nrows) {
      float4* dst = (float4*)&Y[(size_t)gr * H + c0];
      dst[0] = make_float4(acc[rr][0], acc[rr][1], acc[rr][2], acc[rr][3]);
      dst[1] = make_float4(acc[rr][4], acc[rr][5], acc[rr][6], acc[rr][7]);
    }
  }
  // fused column stats: shuffle-reduce over the 4 row-groups within each wave
  float cs[8], cq[8];
#pragma unroll
  for (int j = 0; j < 8; j++) {
    float a0 = ok0 ? acc[0][j] : 0.f;
    float a1 = ok1 ? acc[1][j] : 0.f;
    cs[j] = a0 + a1;
    cq[j] = a0 * a0 + a1 * a1;
  }
#pragma unroll
  for (int j = 0; j < 8; j++) {
    cs[j] += __shfl_down(cs[j], 16, 64);
    cq[j] += __shfl_down(cq[j], 16, 64);
    cs[j] += __shfl_down(cs[j], 32, 64);
    cq[j] += __shfl_down(cq[j], 32, 64);
  }
  int wid = t >> 6;
  int lid = t & 63;
  if (lid < 16) {
#pragma unroll
    for (int j = 0; j < 8; j++) {
      wsum[wid][lid * 8 + j] = cs[j];
      wsq[wid][lid * 8 + j] = cq[j];
    }
  }
  __syncthreads();
  if (t < H) {
    float s = wsum[0][t] + wsum[1][t] + wsum[2][t] + wsum[3][t];
    float q = wsq[0][t] + wsq[1][t] + wsq[2][t] + wsq[3][t];
    atomicAdd(&gstats[t], s);
    atomicAdd(&gstats[H + t], q);
  }
}

// ---------------- BN+relu+vn add + segmented vt scatter (batch sorted) ----------------
__global__ void k_bn_vn2(const float* __restrict__ X, const float* __restrict__ stats,
                         const float* __restrict__ g, const float* __restrict__ bt,
                         const float* __restrict__ vn, const int* __restrict__ batch,
                         float* __restrict__ out, float* __restrict__ vtsum) {
  int c = threadIdx.x;
  int r0 = blockIdx.x * 16;
  int r1 = r0 + 16; if (r1 > NN) r1 = NN;
  const float invN = 1.0f / NN;
  float m = stats[c] * invN;
  float var = stats[H + c] * invN - m * m;
  float rs = rsqrtf(var + EPSV);
  float gc = g[c], bc = bt[c];
  int curb = batch[r0];
  float vnv = vn[curb * H + c];
  float s = 0.f;
  for (int r = r0; r < r1; r++) {
    int b = batch[r];
    if (b != curb) {
      atomicAdd(&vtsum[curb * H + c], s);
      s = 0.f; curb = b; vnv = vn[b * H + c];
    }
    float y = fmaxf(gc * (X[(size_t)r * H + c] - m) * rs + bc, 0.f) + vnv;
    out[(size_t)r * H + c] = y;
    s += y;
  }
  atomicAdd(&vtsum[curb * H + c], s);
}
// BN only, also emits bf16 copy (for APPNP bf16 gathers)
__global__ void k_bn_plain_b(const float* __restrict__ X, const float* __restrict__ stats,
                             const float* __restrict__ g, const float* __restrict__ bt,
                             float* __restrict__ outf, unsigned short* __restrict__ outb) {
  int idx = blockIdx.x * blockDim.x + threadIdx.x;
  if (idx >= NN * H) return;
  int c = idx & (H - 1);
  const float invN = 1.0f / NN;
  float m = stats[c] * invN;
  float var = stats[H + c] * invN - m * m;
  float rs = rsqrtf(var + EPSV);
  float y = g[c] * (X[idx] - m) * rs + bt[c];
  outf[idx] = y;
  outb[idx] = f2b(y);
}
// BN+relu in place, [NG x C]
__global__ void k_bn_small(float* Y, const float* __restrict__ stats,
                           const float* __restrict__ g, const float* __restrict__ bt,
                           int C) {
  int idx = blockIdx.x * blockDim.x + threadIdx.x;
  if (idx >= NG * C) return;
  int c = idx % C;
  const float invN = 1.0f / NG;
  float m = stats[c] * invN;
  float var = stats[C + c] * invN - m * m;
  float rs = rsqrtf(var + EPSV);
  Y[idx] = fmaxf(g[c] * (Y[idx] - m) * rs + bt[c], 0.f);
}
// BN+relu then vn += result, [NG x 128]
__global__ void k_bn_addvn(const float* __restrict__ Y, const float* __restrict__ stats,
                           const float* __restrict__ g, const float* __restrict__ bt,
                           float* vn) {
  int idx = blockIdx.x * blockDim.x + threadIdx.x;
  if (idx >= NG * H) return;
  int c = idx & (H - 1);
  const float invN = 1.0f / NG;
  float m = stats[c] * invN;
  float var = stats[H + c] * invN - m * m;
  float rs = rsqrtf(var + EPSV);
  vn[idx] += fmaxf(g[c] * (Y[idx] - m) * rs + bt[c], 0.f);
}

// ---------------- small matmuls with fused stats ----------------
__global__ void k_mm_vn1(const float* __restrict__ vtsum, const float* __restrict__ vn,
                         const float* __restrict__ W, const float* __restrict__ bias,
                         float* __restrict__ Y, float* __restrict__ gstats) {
  __shared__ float xs[H];
  int r = blockIdx.x, c = threadIdx.x;
  if (c < H) xs[c] = vtsum[r * H + c] + vn[r * H + c];
  __syncthreads();
  float acc = bias[c];
#pragma unroll 16
  for (int k = 0; k < H; k++) acc += xs[k] * W[k * 256 + c];
  Y[r * 256 + c] = acc;
  atomicAdd(&gstats[c], acc);
  atomicAdd(&gstats[256 + c], acc * acc);
}
__global__ void k_mm_vn2(const float* __restrict__ X, const float* __restrict__ W,
                         const float* __restrict__ bias, float* __restrict__ Y,
                         float* __restrict__ gstats) {
  __shared__ float xs[256];
  int r = blockIdx.x, c = threadIdx.x;
  xs[c] = X[r * 256 + c];
  xs[c + 128] = X[r * 256 + c + 128];
  __syncthreads();
  float acc = bias[c];
#pragma unroll 16
  for (int k = 0; k < 256; k++) acc += xs[k] * W[k * H + c];
  Y[r * H + c] = acc;
  atomicAdd(&gstats[c], acc);
  atomicAdd(&gstats[H + c], acc * acc);
}

// ---------------- segmented pooling (batch sorted) ----------------
__global__ void k_pool2(const float* __restrict__ h, const int* __restrict__ batch,
                        float* pooled) {
  int c = threadIdx.x;
  int r0 = blockIdx.x * 16;
  int r1 = r0 + 16; if (r1 > NN) r1 = NN;
  int curb = batch[r0];
  float s = 0.f;
  for (int r = r0; r < r1; r++) {
    int b = batch[r];
    if (b != curb) { atomicAdd(&pooled[curb * H + c], s); s = 0.f; curb = b; }
    s += h[(size_t)r * H + c];
  }
  atomicAdd(&pooled[curb * H + c], s);
}
__global__ void k_head(const float* __restrict__ pooled, const int* __restrict__ gcnt,
                       const float* __restrict__ Wout, const float* __restrict__ bout,
                       float* __restrict__ out) {
  __shared__ float xs[H];
  int r = blockIdx.x, c = threadIdx.x;
  float inv = 1.0f / fmaxf((float)gcnt[r], 1.0f);
  if (c < H) xs[c] = pooled[r * H + c] * inv;
  __syncthreads();
  float acc = bout[c];
#pragma unroll 16
  for (int k = 0; k < H; k++) acc += xs[k] * Wout[k * OUTC + c];
  out[r * OUTC + c] = acc;
}

// ---------------- launch ----------------
extern "C" void kernel_launch(void* const* d_in, const int* in_sizes, int n_in,
                              void* d_out, int out_size, void* d_ws, size_t ws_size,
                              hipStream_t stream) {
  const float* x      = (const float*)d_in[0];
  const int*   ei     = (const int*)d_in[1];
  const int*   e_src  = ei;
  const int*   e_dst  = ei + NE;
  const int*   batch  = (const int*)d_in[2];
  const float* W      = (const float*)d_in[3];
  const float* b      = (const float*)d_in[4];
  const float* gamma  = (const float*)d_in[5];
  const float* beta   = (const float*)d_in[6];
  const float* vn_emb = (const float*)d_in[7];
  const float* W1     = (const float*)d_in[8];
  const float* b1     = (const float*)d_in[9];
  const float* g1     = (const float*)d_in[10];
  const float* bt1    = (const float*)d_in[11];
  const float* W2     = (const float*)d_in[12];
  const float* b2     = (const float*)d_in[13];
  const float* g2     = (const float*)d_in[14];
  const float* bt2    = (const float*)d_in[15];
  const float* Wout   = (const float*)d_in[16];
  const float* bout   = (const float*)d_in[17];
  float* out = (float*)d_out;

  char* p = (char*)d_ws;
  auto alloc = [&](size_t bytes) -> char* {
    char* r = p; p += (bytes + 255) & ~(size_t)255; return r;
  };
  float* hA       = (float*)alloc((size_t)NN * H * 4);
  float* hB       = (float*)alloc((size_t)NN * H * 4);
  float* hC       = (float*)alloc((size_t)NN * H * 4);
  int*   deg      = (int*)alloc((size_t)NN * 4);
  int*   cursor   = (int*)alloc((size_t)NN * 4);
  int*   rowptr   = (int*)alloc((size_t)(NN + 1) * 4);
  int*   gcnt     = (int*)alloc(512 * 4);
  int*   csr_src  = (int*)alloc((size_t)NE * 4);
  float* csr_norm = (float*)alloc((size_t)NE * 4);
  float* dinv     = (float*)alloc((size_t)NN * 4);
  float* vn       = (float*)alloc((size_t)NG * H * 4);
  float* vtsum0   = (float*)alloc((size_t)NG * H * 4);
  float* vtsum1   = (float*)alloc((size_t)NG * H * 4);
  float* t1       = (float*)alloc((size_t)NG * 256 * 4);
  float* t2       = (float*)alloc((size_t)NG * H * 4);
  float* pooled   = (float*)alloc((size_t)NG * H * 4);
  float* stats    = (float*)alloc(9 * 512 * 4);
  int*   bsum     = (int*)alloc(256 * 4);
  int*   boff     = (int*)alloc(256 * 4);

  // bf16 APPNP buffers carved out of hB (free during APPNP; final output -> hC)
  unsigned short* bf0 = (unsigned short*)hB;
  unsigned short* bf1 = (unsigned short*)hB + (size_t)NN * H;

  const int B = 256;
  const int gNN   = (NN + B - 1) / B;
  const int gNE   = (NE + B - 1) / B;
  const int gELT  = (NN * H + B - 1) / B;
  const int gVN   = (NG * H + B - 1) / B;
  const int gSEG  = (NN + 15) / 16;            // 3125
  const int gPROP = NN / 8;                    // 6250
  const int mmGrid = (NN + 31) / 32;

  // ---- init + graph preprocessing ----
  k_init<<<(NG * H + B - 1) / B, B, 0, stream>>>(deg, cursor, gcnt, stats, vtsum0, vtsum1,
                                                 pooled, vn_emb, vn);
  k_hist_edges<<<gNE, B, 0, stream>>>(e_dst, deg);
  k_hist_batch<<<gNN, B, 0, stream>>>(batch, gcnt);
  k_dinv<<<gNN, B, 0, stream>>>(deg, dinv);
  k_scan1<<<NB1, 256, 0, stream>>>(deg, bsum);
  k_scan2<<<1, 256, 0, stream>>>(bsum, boff);
  k_scan3<<<NB1, 256, 0, stream>>>(deg, boff, rowptr);
  k_fill_csr<<<gNE, B, 0, stream>>>(e_src, e_dst, dinv, rowptr, cursor, csr_src, csr_norm);

  float* st[7];
  for (int i = 0; i < 7; i++) st[i] = stats + i * 512;

  // ---- conv layers 0,1 with virtual node MLP ----
  const float* cur = x;
  float* vts[2] = {vtsum0, vtsum1};
  for (int i = 0; i < 2; i++) {
    int j = (i == 0) ? 1 : 0;
    k_prop<<<gPROP, 256, 0, stream>>>(cur, hB, rowptr, csr_src, csr_norm, dinv);
    k_mm_node<<<mmGrid, 256, 0, stream>>>(hB, W + (size_t)i * H * H, b + i * H, hC, NN, st[3 * i]);
    k_bn_vn2<<<gSEG, H, 0, stream>>>(hC, st[3 * i], gamma + i * H, beta + i * H, vn, batch, hA, vts[i]);
    k_mm_vn1<<<NG, 256, 0, stream>>>(vts[i], vn, W1 + (size_t)j * H * 256, b1 + j * 256, t1, st[3 * i + 1]);
    k_bn_small<<<(NG * 256 + B - 1) / B, B, 0, stream>>>(t1, st[3 * i + 1], g1 + j * 256, bt1 + j * 256, 256);
    k_mm_vn2<<<NG, 128, 0, stream>>>(t1, W2 + (size_t)j * 256 * H, b2 + j * H, t2, st[3 * i + 2]);
    k_bn_addvn<<<gVN, B, 0, stream>>>(t2, st[3 * i + 2], g2 + j * H, bt2 + j * H, vn);
    cur = hA;
  }

  // ---- last conv layer: prop, matmul, BN (fp32 hA + bf16 bf0) ----
  k_prop<<<gPROP, 256, 0, stream>>>(hA, hB, rowptr, csr_src, csr_norm, dinv);
  k_mm_node<<<mmGrid, 256, 0, stream>>>(hB, W + (size_t)2 * H * H, b + 2 * H, hC, NN, st[6]);
  k_bn_plain_b<<<gELT, B, 0, stream>>>(hC, st[6], gamma + 2 * H, beta + 2 * H, hA, bf0);

  // ---- APPNP: h0 = hA (fp32), iterate in bf16, final -> hC (fp32) ----
  k_prop_b<<<gPROP, 256, 0, stream>>>(bf0, hA, bf1, nullptr, rowptr, csr_src, csr_norm, dinv);
  k_prop_b<<<gPROP, 256, 0, stream>>>(bf1, hA, bf0, nullptr, rowptr, csr_src, csr_norm, dinv);
  k_prop_b<<<gPROP, 256, 0, stream>>>(bf0, hA, bf1, nullptr, rowptr, csr_src, csr_norm, dinv);
  k_prop_b<<<gPROP, 256, 0, stream>>>(bf1, hA, bf0, nullptr, rowptr, csr_src, csr_norm, dinv);
  k_prop_b<<<gPROP, 256, 0, stream>>>(bf0, hA, nullptr, hC, rowptr, csr_src, csr_norm, dinv);

  // ---- mean pool + head ----
  k_pool2<<<gSEG, H, 0, stream>>>(hC, batch, pooled);
  k_head<<<NG, OUTC, 0, stream>>>(pooled, gcnt, Wout, bout, out);
}

// Round 5
// 752.315 us; speedup vs baseline: 1.7901x; 1.0350x over previous
//
#include <hip/hip_runtime.h>
#include <cstddef>
#include <cstdint>

#define NN 50000
#define NE 600000
#define H 128
#define NG 512
#define OUTC 128
#define EPSV 1e-5f
#define NB1 196   // ceil(NN/256)

typedef __attribute__((ext_vector_type(8))) short bf16x8;
typedef __attribute__((ext_vector_type(4))) float f32x4;

__device__ __forceinline__ unsigned short f2b(float f) {
  uint32_t u = __float_as_uint(f);
  uint32_t r = u + 0x7FFFu + ((u >> 16) & 1u);
  return (unsigned short)(r >> 16);
}
__device__ __forceinline__ float4 b4_to_f4(uint2 v) {
  float4 f;
  f.x = __uint_as_float(v.x << 16);
  f.y = __uint_as_float(v.x & 0xFFFF0000u);
  f.z = __uint_as_float(v.y << 16);
  f.w = __uint_as_float(v.y & 0xFFFF0000u);
  return f;
}
__device__ __forceinline__ uint2 f4_to_b4(float4 r) {
  uint2 o;
  o.x = (uint32_t)f2b(r.x) | ((uint32_t)f2b(r.y) << 16);
  o.y = (uint32_t)f2b(r.z) | ((uint32_t)f2b(r.w) << 16);
  return o;
}

// ---------------- combined init ----------------
__global__ void k_init(int* deg, int* cursor, int* gcnt, float* stats,
                       float* vtsum0, float* vtsum1, float* pooled,
                       const float* __restrict__ vn_emb, float* vn) {
  int i = blockIdx.x * blockDim.x + threadIdx.x;
  if (i < NN) { deg[i] = 1; cursor[i] = 0; }
  if (i < NG) gcnt[i] = 0;
  if (i < 9 * 512) stats[i] = 0.f;
  if (i < NG * H) {
    vtsum0[i] = 0.f; vtsum1[i] = 0.f; pooled[i] = 0.f;
    vn[i] = vn_emb[i & (H - 1)];
  }
}

// ---------------- W -> bf16 W^T conversion: WT[i][n*128+k] = bf16(W[i][k*128+n]) ----------------
__global__ void k_wconv(const float* __restrict__ W, unsigned short* __restrict__ WT) {
  int idx = blockIdx.x * blockDim.x + threadIdx.x;
  if (idx >= 3 * H * H) return;
  int i = idx >> 14;            // /16384
  int rem = idx & 16383;
  int n = rem >> 7, k = rem & 127;
  WT[idx] = f2b(W[i * H * H + k * H + n]);
}

// ---------------- graph preprocessing ----------------
__global__ void k_hist_edges(const int* __restrict__ dst, int* deg) {
  int e = blockIdx.x * blockDim.x + threadIdx.x;
  if (e < NE) atomicAdd(&deg[dst[e]], 1);
}
__global__ void k_hist_batch(const int* __restrict__ batch, int* gcnt) {
  int n = blockIdx.x * blockDim.x + threadIdx.x;
  if (n < NN) atomicAdd(&gcnt[batch[n]], 1);
}
__global__ void k_dinv(const int* __restrict__ deg, float* dinv) {
  int i = blockIdx.x * blockDim.x + threadIdx.x;
  if (i < NN) dinv[i] = rsqrtf((float)deg[i]);
}
__global__ void k_scan1(const int* __restrict__ deg, int* bsum) {
  __shared__ int sh[256];
  int t = threadIdx.x;
  int i = blockIdx.x * 256 + t;
  sh[t] = (i < NN) ? deg[i] - 1 : 0;
  __syncthreads();
  for (int o = 128; o > 0; o >>= 1) {
    if (t < o) sh[t] += sh[t + o];
    __syncthreads();
  }
  if (t == 0) bsum[blockIdx.x] = sh[0];
}
__global__ void k_scan2(const int* __restrict__ bsum, int* boff) {
  __shared__ int sh[256];
  int t = threadIdx.x;
  int v = (t < NB1) ? bsum[t] : 0;
  sh[t] = v;
  __syncthreads();
  for (int o = 1; o < 256; o <<= 1) {
    int u = (t >= o) ? sh[t - o] : 0;
    __syncthreads();
    sh[t] += u;
    __syncthreads();
  }
  if (t < NB1) boff[t] = sh[t] - v;
}
__global__ void k_scan3(const int* __restrict__ deg, const int* __restrict__ boff,
                        int* __restrict__ rowptr) {
  __shared__ int sh[256];
  int t = threadIdx.x;
  int i = blockIdx.x * 256 + t;
  int v = (i < NN) ? deg[i] - 1 : 0;
  sh[t] = v;
  __syncthreads();
  for (int o = 1; o < 256; o <<= 1) {
    int u = (t >= o) ? sh[t - o] : 0;
    __syncthreads();
    sh[t] += u;
    __syncthreads();
  }
  if (i < NN) rowptr[i] = boff[blockIdx.x] + sh[t] - v;
  if (i == NN - 1) rowptr[NN] = boff[blockIdx.x] + sh[t];
}
__global__ void k_fill_csr(const int* __restrict__ src, const int* __restrict__ dst,
                           const float* __restrict__ dinv, const int* __restrict__ rowptr,
                           int* cursor, int* __restrict__ csr_src, float* __restrict__ csr_norm) {
  int e = blockIdx.x * blockDim.x + threadIdx.x;
  if (e >= NE) return;
  int s = src[e], d = dst[e];
  int pos = rowptr[d] + atomicAdd(&cursor[d], 1);
  csr_src[pos] = s;
  csr_norm[pos] = dinv[s] * dinv[d];
}

// ---------------- fp32-gather propagation, bf16 output (feeds MFMA matmul) ----------------
__global__ __launch_bounds__(256) void k_prop(const float* __restrict__ h,
    unsigned short* __restrict__ outb,
    const int* __restrict__ rowptr, const int* __restrict__ csr_src,
    const float* __restrict__ csr_norm, const float* __restrict__ dinv) {
  int lane = threadIdx.x & 31;
  int d = blockIdx.x * 8 + (threadIdx.x >> 5);
  const float4* h4 = (const float4*)h;
  float dv = dinv[d];
  size_t drow = (size_t)d * 32 + lane;
  float4 v = h4[drow];
  float w = dv * dv;
  float4 acc = make_float4(w * v.x, w * v.y, w * v.z, w * v.w);
  int e = rowptr[d], e1 = rowptr[d + 1];
  for (; e + 7 < e1; e += 8) {
    int   si[8]; float nm[8]; float4 g[8];
#pragma unroll
    for (int u = 0; u < 8; u++) { si[u] = csr_src[e + u]; nm[u] = csr_norm[e + u]; }
#pragma unroll
    for (int u = 0; u < 8; u++) g[u] = h4[(size_t)si[u] * 32 + lane];
#pragma unroll
    for (int u = 0; u < 8; u++) {
      acc.x += nm[u] * g[u].x; acc.y += nm[u] * g[u].y;
      acc.z += nm[u] * g[u].z; acc.w += nm[u] * g[u].w;
    }
  }
  if (e + 3 < e1) {
    int   si[4]; float nm[4]; float4 g[4];
#pragma unroll
    for (int u = 0; u < 4; u++) { si[u] = csr_src[e + u]; nm[u] = csr_norm[e + u]; }
#pragma unroll
    for (int u = 0; u < 4; u++) g[u] = h4[(size_t)si[u] * 32 + lane];
#pragma unroll
    for (int u = 0; u < 4; u++) {
      acc.x += nm[u] * g[u].x; acc.y += nm[u] * g[u].y;
      acc.z += nm[u] * g[u].z; acc.w += nm[u] * g[u].w;
    }
    e += 4;
  }
  for (; e < e1; e++) {
    int s = csr_src[e];
    float nn = csr_norm[e];
    float4 a = h4[(size_t)s * 32 + lane];
    acc.x += nn * a.x; acc.y += nn * a.y; acc.z += nn * a.z; acc.w += nn * a.w;
  }
  ((uint2*)outb)[drow] = f4_to_b4(acc);
}

// ---------------- bf16-gather APPNP propagation ----------------
__global__ __launch_bounds__(256) void k_prop_b(const unsigned short* __restrict__ hb,
    const float* __restrict__ base, unsigned short* __restrict__ outb,
    float* __restrict__ outf,
    const int* __restrict__ rowptr, const int* __restrict__ csr_src,
    const float* __restrict__ csr_norm, const float* __restrict__ dinv) {
  int lane = threadIdx.x & 31;
  int d = blockIdx.x * 8 + (threadIdx.x >> 5);
  const uint2* h2 = (const uint2*)hb;
  float dv = dinv[d];
  size_t drow = (size_t)d * 32 + lane;
  float4 v = b4_to_f4(h2[drow]);
  float w = dv * dv;
  float4 acc = make_float4(w * v.x, w * v.y, w * v.z, w * v.w);
  int e = rowptr[d], e1 = rowptr[d + 1];
  for (; e + 7 < e1; e += 8) {
    int   si[8]; float nm[8]; uint2 g[8];
#pragma unroll
    for (int u = 0; u < 8; u++) { si[u] = csr_src[e + u]; nm[u] = csr_norm[e + u]; }
#pragma unroll
    for (int u = 0; u < 8; u++) g[u] = h2[(size_t)si[u] * 32 + lane];
#pragma unroll
    for (int u = 0; u < 8; u++) {
      float4 f = b4_to_f4(g[u]);
      acc.x += nm[u] * f.x; acc.y += nm[u] * f.y;
      acc.z += nm[u] * f.z; acc.w += nm[u] * f.w;
    }
  }
  if (e + 3 < e1) {
    int   si[4]; float nm[4]; uint2 g[4];
#pragma unroll
    for (int u = 0; u < 4; u++) { si[u] = csr_src[e + u]; nm[u] = csr_norm[e + u]; }
#pragma unroll
    for (int u = 0; u < 4; u++) g[u] = h2[(size_t)si[u] * 32 + lane];
#pragma unroll
    for (int u = 0; u < 4; u++) {
      float4 f = b4_to_f4(g[u]);
      acc.x += nm[u] * f.x; acc.y += nm[u] * f.y;
      acc.z += nm[u] * f.z; acc.w += nm[u] * f.w;
    }
    e += 4;
  }
  for (; e < e1; e++) {
    int s = csr_src[e];
    float nn = csr_norm[e];
    float4 f = b4_to_f4(h2[(size_t)s * 32 + lane]);
    acc.x += nn * f.x; acc.y += nn * f.y; acc.z += nn * f.z; acc.w += nn * f.w;
  }
  float4 bb = ((const float4*)base)[drow];
  float4 r;
  r.x = 0.2f * acc.x + 0.8f * bb.x;
  r.y = 0.2f * acc.y + 0.8f * bb.y;
  r.z = 0.2f * acc.z + 0.8f * bb.z;
  r.w = 0.2f * acc.w + 0.8f * bb.w;
  if (outb) {
    ((uint2*)outb)[drow] = f4_to_b4(r);
  } else {
    ((float4*)outf)[drow] = r;
  }
}

// ---------------- MFMA node matmul: Y[NN x 128] = A(bf16) @ W + bias, fused stats ----------------
// A row-major bf16; WT is W^T in bf16 (WT[n*128+k] = W[k][n]).
// Block: 256 thr = 4 waves; wave (wm,wn) computes rows rbase+16*wm.., cols 64*wn..+63.
__global__ __launch_bounds__(256) void k_mm_mfma(const unsigned short* __restrict__ A,
    const unsigned short* __restrict__ WT, const float* __restrict__ bias,
    float* __restrict__ Y, float* __restrict__ gstats) {
  __shared__ float csum[H];
  __shared__ float csqs[H];
  int t = threadIdx.x;
  int lane = t & 63;
  int w = t >> 6;
  int wm = w & 1, wn = w >> 1;
  int rbase = blockIdx.x * 32 + wm * 16;
  int col0 = wn * 64;
  int l15 = lane & 15;
  int quad = lane >> 4;
  if (t < H) { csum[t] = 0.f; csqs[t] = 0.f; }

  f32x4 acc[4];
#pragma unroll
  for (int tt = 0; tt < 4; tt++) {
    float bb = bias[col0 + 16 * tt + l15];
    acc[tt][0] = bb; acc[tt][1] = bb; acc[tt][2] = bb; acc[tt][3] = bb;
  }
  // A fragment rows: rbase + l15 (clamped for OOB safety; results masked later)
  int arow = rbase + l15; if (arow >= NN) arow = NN - 1;
  const bf16x8* Arow = (const bf16x8*)(A + (size_t)arow * H);
  const bf16x8* B0 = (const bf16x8*)(WT + (size_t)(col0 + l15) * H);
  const bf16x8* B1 = (const bf16x8*)(WT + (size_t)(col0 + 16 + l15) * H);
  const bf16x8* B2 = (const bf16x8*)(WT + (size_t)(col0 + 32 + l15) * H);
  const bf16x8* B3 = (const bf16x8*)(WT + (size_t)(col0 + 48 + l15) * H);
#pragma unroll
  for (int k0 = 0; k0 < 4; k0++) {
    bf16x8 a = Arow[k0 * 4 + quad];
    acc[0] = __builtin_amdgcn_mfma_f32_16x16x32_bf16(a, B0[k0 * 4 + quad], acc[0], 0, 0, 0);
    acc[1] = __builtin_amdgcn_mfma_f32_16x16x32_bf16(a, B1[k0 * 4 + quad], acc[1], 0, 0, 0);
    acc[2] = __builtin_amdgcn_mfma_f32_16x16x32_bf16(a, B2[k0 * 4 + quad], acc[2], 0, 0, 0);
    acc[3] = __builtin_amdgcn_mfma_f32_16x16x32_bf16(a, B3[k0 * 4 + quad], acc[3], 0, 0, 0);
  }
  // C/D layout: col = lane&15, row = quad*4 + reg
  __syncthreads();  // csum/csqs init visible
#pragma unroll
  for (int tt = 0; tt < 4; tt++) {
    int col = col0 + 16 * tt + l15;
    float s = 0.f, q = 0.f;
#pragma unroll
    for (int r = 0; r < 4; r++) {
      int grow = rbase + quad * 4 + r;
      float v = acc[tt][r];
      if (grow < NN) {
        Y[(size_t)grow * H + col] = v;
        s += v; q += v * v;
      }
    }
    // reduce over quads (lanes +16,+32 share col)
    s += __shfl_down(s, 16, 64); q += __shfl_down(q, 16, 64);
    s += __shfl_down(s, 32, 64); q += __shfl_down(q, 32, 64);
    if (quad == 0) {
      atomicAdd(&csum[col], s);
      atomicAdd(&csqs[col], q);
    }
  }
  __syncthreads();
  if (t < H) {
    atomicAdd(&gstats[t], csum[t]);
    atomicAdd(&gstats[H + t], csqs[t]);
  }
}

// ---------------- BN+relu+vn add + segmented vt scatter (batch sorted) ----------------
__global__ void k_bn_vn2(const float* __restrict__ X, const float* __restrict__ stats,
                         const float* __restrict__ g, const float* __restrict__ bt,
                         const float* __restrict__ vn, const int* __restrict__ batch,
                         float* __restrict__ out, float* __restrict__ vtsum) {
  int c = threadIdx.x;
  int r0 = blockIdx.x * 16;
  int r1 = r0 + 16; if (r1 > NN) r1 = NN;
  const float invN = 1.0f / NN;
  float m = stats[c] * invN;
  float var = stats[H + c] * invN - m * m;
  float rs = rsqrtf(var + EPSV);
  float gc = g[c], bc = bt[c];
  int curb = batch[r0];
  float vnv = vn[curb * H + c];
  float s = 0.f;
  for (int r = r0; r < r1; r++) {
    int b = batch[r];
    if (b != curb) {
      atomicAdd(&vtsum[curb * H + c], s);
      s = 0.f; curb = b; vnv = vn[b * H + c];
    }
    float y = fmaxf(gc * (X[(size_t)r * H + c] - m) * rs + bc, 0.f) + vnv;
    out[(size_t)r * H + c] = y;
    s += y;
  }
  atomicAdd(&vtsum[curb * H + c], s);
}
// BN only, also emits bf16 copy (for APPNP bf16 gathers)
__global__ void k_bn_plain_b(const float* __restrict__ X, const float* __restrict__ stats,
                             const float* __restrict__ g, const float* __restrict__ bt,
                             float* __restrict__ outf, unsigned short* __restrict__ outb) {
  int idx = blockIdx.x * blockDim.x + threadIdx.x;
  if (idx >= NN * H) return;
  int c = idx & (H - 1);
  const float invN = 1.0f / NN;
  float m = stats[c] * invN;
  float var = stats[H + c] * invN - m * m;
  float rs = rsqrtf(var + EPSV);
  float y = g[c] * (X[idx] - m) * rs + bt[c];
  outf[idx] = y;
  outb[idx] = f2b(y);
}
// BN+relu in place, [NG x C]
__global__ void k_bn_small(float* Y, const float* __restrict__ stats,
                           const float* __restrict__ g, const float* __restrict__ bt,
                           int C) {
  int idx = blockIdx.x * blockDim.x + threadIdx.x;
  if (idx >= NG * C) return;
  int c = idx % C;
  const float invN = 1.0f / NG;
  float m = stats[c] * invN;
  float var = stats[C + c] * invN - m * m;
  float rs = rsqrtf(var + EPSV);
  Y[idx] = fmaxf(g[c] * (Y[idx] - m) * rs + bt[c], 0.f);
}
// BN+relu then vn += result, [NG x 128]
__global__ void k_bn_addvn(const float* __restrict__ Y, const float* __restrict__ stats,
                           const float* __restrict__ g, const float* __restrict__ bt,
                           float* vn) {
  int idx = blockIdx.x * blockDim.x + threadIdx.x;
  if (idx >= NG * H) return;
  int c = idx & (H - 1);
  const float invN = 1.0f / NG;
  float m = stats[c] * invN;
  float var = stats[H + c] * invN - m * m;
  float rs = rsqrtf(var + EPSV);
  vn[idx] += fmaxf(g[c] * (Y[idx] - m) * rs + bt[c], 0.f);
}

// ---------------- small matmuls with fused stats ----------------
__global__ void k_mm_vn1(const float* __restrict__ vtsum, const float* __restrict__ vn,
                         const float* __restrict__ W, const float* __restrict__ bias,
                         float* __restrict__ Y, float* __restrict__ gstats) {
  __shared__ float xs[H];
  int r = blockIdx.x, c = threadIdx.x;
  if (c < H) xs[c] = vtsum[r * H + c] + vn[r * H + c];
  __syncthreads();
  float acc = bias[c];
#pragma unroll 16
  for (int k = 0; k < H; k++) acc += xs[k] * W[k * 256 + c];
  Y[r * 256 + c] = acc;
  atomicAdd(&gstats[c], acc);
  atomicAdd(&gstats[256 + c], acc * acc);
}
__global__ void k_mm_vn2(const float* __restrict__ X, const float* __restrict__ W,
                         const float* __restrict__ bias, float* __restrict__ Y,
                         float* __restrict__ gstats) {
  __shared__ float xs[256];
  int r = blockIdx.x, c = threadIdx.x;
  xs[c] = X[r * 256 + c];
  xs[c + 128] = X[r * 256 + c + 128];
  __syncthreads();
  float acc = bias[c];
#pragma unroll 16
  for (int k = 0; k < 256; k++) acc += xs[k] * W[k * H + c];
  Y[r * H + c] = acc;
  atomicAdd(&gstats[c], acc);
  atomicAdd(&gstats[H + c], acc * acc);
}

// ---------------- segmented pooling (batch sorted) ----------------
__global__ void k_pool2(const float* __restrict__ h, const int* __restrict__ batch,
                        float* pooled) {
  int c = threadIdx.x;
  int r0 = blockIdx.x * 16;
  int r1 = r0 + 16; if (r1 > NN) r1 = NN;
  int curb = batch[r0];
  float s = 0.f;
  for (int r = r0; r < r1; r++) {
    int b = batch[r];
    if (b != curb) { atomicAdd(&pooled[curb * H + c], s); s = 0.f; curb = b; }
    s += h[(size_t)r * H + c];
  }
  atomicAdd(&pooled[curb * H + c], s);
}
__global__ void k_head(const float* __restrict__ pooled, const int* __restrict__ gcnt,
                       const float* __restrict__ Wout, const float* __restrict__ bout,
                       float* __restrict__ out) {
  __shared__ float xs[H];
  int r = blockIdx.x, c = threadIdx.x;
  float inv = 1.0f / fmaxf((float)gcnt[r], 1.0f);
  if (c < H) xs[c] = pooled[r * H + c] * inv;
  __syncthreads();
  float acc = bout[c];
#pragma unroll 16
  for (int k = 0; k < H; k++) acc += xs[k] * Wout[k * OUTC + c];
  out[r * OUTC + c] = acc;
}

// ---------------- launch ----------------
extern "C" void kernel_launch(void* const* d_in, const int* in_sizes, int n_in,
                              void* d_out, int out_size, void* d_ws, size_t ws_size,
                              hipStream_t stream) {
  const float* x      = (const float*)d_in[0];
  const int*   ei     = (const int*)d_in[1];
  const int*   e_src  = ei;
  const int*   e_dst  = ei + NE;
  const int*   batch  = (const int*)d_in[2];
  const float* W      = (const float*)d_in[3];
  const float* b      = (const float*)d_in[4];
  const float* gamma  = (const float*)d_in[5];
  const float* beta   = (const float*)d_in[6];
  const float* vn_emb = (const float*)d_in[7];
  const float* W1     = (const float*)d_in[8];
  const float* b1     = (const float*)d_in[9];
  const float* g1     = (const float*)d_in[10];
  const float* bt1    = (const float*)d_in[11];
  const float* W2     = (const float*)d_in[12];
  const float* b2     = (const float*)d_in[13];
  const float* g2     = (const float*)d_in[14];
  const float* bt2    = (const float*)d_in[15];
  const float* Wout   = (const float*)d_in[16];
  const float* bout   = (const float*)d_in[17];
  float* out = (float*)d_out;

  char* p = (char*)d_ws;
  auto alloc = [&](size_t bytes) -> char* {
    char* r = p; p += (bytes + 255) & ~(size_t)255; return r;
  };
  float* hA       = (float*)alloc((size_t)NN * H * 4);
  float* hB       = (float*)alloc((size_t)NN * H * 4);
  float* hC       = (float*)alloc((size_t)NN * H * 4);
  int*   deg      = (int*)alloc((size_t)NN * 4);
  int*   cursor   = (int*)alloc((size_t)NN * 4);
  int*   rowptr   = (int*)alloc((size_t)(NN + 1) * 4);
  int*   gcnt     = (int*)alloc(512 * 4);
  int*   csr_src  = (int*)alloc((size_t)NE * 4);
  float* csr_norm = (float*)alloc((size_t)NE * 4);
  float* dinv     = (float*)alloc((size_t)NN * 4);
  float* vn       = (float*)alloc((size_t)NG * H * 4);
  float* vtsum0   = (float*)alloc((size_t)NG * H * 4);
  float* vtsum1   = (float*)alloc((size_t)NG * H * 4);
  float* t1       = (float*)alloc((size_t)NG * 256 * 4);
  float* t2       = (float*)alloc((size_t)NG * H * 4);
  float* pooled   = (float*)alloc((size_t)NG * H * 4);
  float* stats    = (float*)alloc(9 * 512 * 4);
  int*   bsum     = (int*)alloc(256 * 4);
  int*   boff     = (int*)alloc(256 * 4);
  unsigned short* WT = (unsigned short*)alloc((size_t)3 * H * H * 2);

  // bf16 buffers carved out of hB (hB fp32 unused now)
  unsigned short* bf0 = (unsigned short*)hB;                    // conv-prop out / APPNP ping
  unsigned short* bf1 = (unsigned short*)hB + (size_t)NN * H;   // APPNP pong

  const int B = 256;
  const int gNN   = (NN + B - 1) / B;
  const int gNE   = (NE + B - 1) / B;
  const int gELT  = (NN * H + B - 1) / B;
  const int gVN   = (NG * H + B - 1) / B;
  const int gSEG  = (NN + 15) / 16;            // 3125
  const int gPROP = NN / 8;                    // 6250
  const int mmGrid = (NN + 31) / 32;           // 1563

  // ---- init + graph preprocessing ----
  k_init<<<(NG * H + B - 1) / B, B, 0, stream>>>(deg, cursor, gcnt, stats, vtsum0, vtsum1,
                                                 pooled, vn_emb, vn);
  k_wconv<<<(3 * H * H + B - 1) / B, B, 0, stream>>>(W, WT);
  k_hist_edges<<<gNE, B, 0, stream>>>(e_dst, deg);
  k_hist_batch<<<gNN, B, 0, stream>>>(batch, gcnt);
  k_dinv<<<gNN, B, 0, stream>>>(deg, dinv);
  k_scan1<<<NB1, 256, 0, stream>>>(deg, bsum);
  k_scan2<<<1, 256, 0, stream>>>(bsum, boff);
  k_scan3<<<NB1, 256, 0, stream>>>(deg, boff, rowptr);
  k_fill_csr<<<gNE, B, 0, stream>>>(e_src, e_dst, dinv, rowptr, cursor, csr_src, csr_norm);

  float* st[7];
  for (int i = 0; i < 7; i++) st[i] = stats + i * 512;

  // ---- conv layers 0,1 with virtual node MLP ----
  const float* cur = x;
  float* vts[2] = {vtsum0, vtsum1};
  for (int i = 0; i < 2; i++) {
    int j = (i == 0) ? 1 : 0;
    k_prop<<<gPROP, 256, 0, stream>>>(cur, bf0, rowptr, csr_src, csr_norm, dinv);
    k_mm_mfma<<<mmGrid, 256, 0, stream>>>(bf0, WT + (size_t)i * H * H, b + i * H, hC, st[3 * i]);
    k_bn_vn2<<<gSEG, H, 0, stream>>>(hC, st[3 * i], gamma + i * H, beta + i * H, vn, batch, hA, vts[i]);
    k_mm_vn1<<<NG, 256, 0, stream>>>(vts[i], vn, W1 + (size_t)j * H * 256, b1 + j * 256, t1, st[3 * i + 1]);
    k_bn_small<<<(NG * 256 + B - 1) / B, B, 0, stream>>>(t1, st[3 * i + 1], g1 + j * 256, bt1 + j * 256, 256);
    k_mm_vn2<<<NG, 128, 0, stream>>>(t1, W2 + (size_t)j * 256 * H, b2 + j * H, t2, st[3 * i + 2]);
    k_bn_addvn<<<gVN, B, 0, stream>>>(t2, st[3 * i + 2], g2 + j * H, bt2 + j * H, vn);
    cur = hA;
  }

  // ---- last conv layer: prop(bf16 out), MFMA matmul, BN (fp32 hA + bf16 bf0) ----
  k_prop<<<gPROP, 256, 0, stream>>>(hA, bf0, rowptr, csr_src, csr_norm, dinv);
  k_mm_mfma<<<mmGrid, 256, 0, stream>>>(bf0, WT + (size_t)2 * H * H, b + 2 * H, hC, st[6]);
  k_bn_plain_b<<<gELT, B, 0, stream>>>(hC, st[6], gamma + 2 * H, beta + 2 * H, hA, bf0);

  // ---- APPNP: h0 = hA (fp32), iterate in bf16, final -> hC (fp32) ----
  k_prop_b<<<gPROP, 256, 0, stream>>>(bf0, hA, bf1, nullptr, rowptr, csr_src, csr_norm, dinv);
  k_prop_b<<<gPROP, 256, 0, stream>>>(bf1, hA, bf0, nullptr, rowptr, csr_src, csr_norm, dinv);
  k_prop_b<<<gPROP, 256, 0, stream>>>(bf0, hA, bf1, nullptr, rowptr, csr_src, csr_norm, dinv);
  k_prop_b<<<gPROP, 256, 0, stream>>>(bf1, hA, bf0, nullptr, rowptr, csr_src, csr_norm, dinv);
  k_prop_b<<<gPROP, 256, 0, stream>>>(bf0, hA, nullptr, hC, rowptr, csr_src, csr_norm, dinv);

  // ---- mean pool + head ----
  k_pool2<<<gSEG, H, 0, stream>>>(hC, batch, pooled);
  k_head<<<NG, OUTC, 0, stream>>>(pooled, gcnt, Wout, bout, out);
}

// Round 6
// 661.691 us; speedup vs baseline: 2.0353x; 1.1370x over previous
//
#include <hip/hip_runtime.h>
#include <cstddef>
#include <cstdint>

#define NN 50000
#define NE 600000
#define H 128
#define NG 512
#define OUTC 128
#define EPSV 1e-5f
#define NB1 196   // ceil(NN/256)
#define MMB 1563  // ceil(NN/32)

typedef __attribute__((ext_vector_type(8))) short bf16x8;
typedef __attribute__((ext_vector_type(4))) float f32x4;

__device__ __forceinline__ unsigned short f2b(float f) {
  uint32_t u = __float_as_uint(f);
  uint32_t r = u + 0x7FFFu + ((u >> 16) & 1u);
  return (unsigned short)(r >> 16);
}
__device__ __forceinline__ float4 b4_to_f4(uint2 v) {
  float4 f;
  f.x = __uint_as_float(v.x << 16);
  f.y = __uint_as_float(v.x & 0xFFFF0000u);
  f.z = __uint_as_float(v.y << 16);
  f.w = __uint_as_float(v.y & 0xFFFF0000u);
  return f;
}
__device__ __forceinline__ uint2 f4_to_b4(float4 r) {
  uint2 o;
  o.x = (uint32_t)f2b(r.x) | ((uint32_t)f2b(r.y) << 16);
  o.y = (uint32_t)f2b(r.z) | ((uint32_t)f2b(r.w) << 16);
  return o;
}

// ---------------- combined init ----------------
__global__ void k_init(int* deg, int* cursor, int* gcnt, float* stats,
                       float* vtsum0, float* vtsum1, float* pooled,
                       const float* __restrict__ vn_emb, float* vn) {
  int i = blockIdx.x * blockDim.x + threadIdx.x;
  if (i < NN) { deg[i] = 1; cursor[i] = 0; }
  if (i < NG) gcnt[i] = 0;
  if (i < 9 * 512) stats[i] = 0.f;
  if (i < NG * H) {
    vtsum0[i] = 0.f; vtsum1[i] = 0.f; pooled[i] = 0.f;
    vn[i] = vn_emb[i & (H - 1)];
  }
}

// ---------------- conversions ----------------
__global__ void k_wconv(const float* __restrict__ W, unsigned short* __restrict__ WT) {
  int idx = blockIdx.x * blockDim.x + threadIdx.x;
  if (idx >= 3 * H * H) return;
  int i = idx >> 14;
  int rem = idx & 16383;
  int n = rem >> 7, k = rem & 127;
  WT[idx] = f2b(W[i * H * H + k * H + n]);
}
__global__ void k_xconv(const float* __restrict__ x, unsigned short* __restrict__ xb) {
  int i = blockIdx.x * blockDim.x + threadIdx.x;
  if (i >= NN * H / 4) return;
  ((uint2*)xb)[i] = f4_to_b4(((const float4*)x)[i]);
}

// ---------------- graph preprocessing ----------------
__global__ void k_hist_edges(const int* __restrict__ dst, int* deg) {
  int e = blockIdx.x * blockDim.x + threadIdx.x;
  if (e < NE) atomicAdd(&deg[dst[e]], 1);
}
__global__ void k_hist_batch(const int* __restrict__ batch, int* gcnt) {
  int n = blockIdx.x * blockDim.x + threadIdx.x;
  if (n < NN) atomicAdd(&gcnt[batch[n]], 1);
}
__global__ void k_dinv(const int* __restrict__ deg, float* dinv) {
  int i = blockIdx.x * blockDim.x + threadIdx.x;
  if (i < NN) dinv[i] = rsqrtf((float)deg[i]);
}
__global__ void k_scan1(const int* __restrict__ deg, int* bsum) {
  __shared__ int sh[256];
  int t = threadIdx.x;
  int i = blockIdx.x * 256 + t;
  sh[t] = (i < NN) ? deg[i] - 1 : 0;
  __syncthreads();
  for (int o = 128; o > 0; o >>= 1) {
    if (t < o) sh[t] += sh[t + o];
    __syncthreads();
  }
  if (t == 0) bsum[blockIdx.x] = sh[0];
}
__global__ void k_scan2(const int* __restrict__ bsum, int* boff) {
  __shared__ int sh[256];
  int t = threadIdx.x;
  int v = (t < NB1) ? bsum[t] : 0;
  sh[t] = v;
  __syncthreads();
  for (int o = 1; o < 256; o <<= 1) {
    int u = (t >= o) ? sh[t - o] : 0;
    __syncthreads();
    sh[t] += u;
    __syncthreads();
  }
  if (t < NB1) boff[t] = sh[t] - v;
}
__global__ void k_scan3(const int* __restrict__ deg, const int* __restrict__ boff,
                        int* __restrict__ rowptr) {
  __shared__ int sh[256];
  int t = threadIdx.x;
  int i = blockIdx.x * 256 + t;
  int v = (i < NN) ? deg[i] - 1 : 0;
  sh[t] = v;
  __syncthreads();
  for (int o = 1; o < 256; o <<= 1) {
    int u = (t >= o) ? sh[t - o] : 0;
    __syncthreads();
    sh[t] += u;
    __syncthreads();
  }
  if (i < NN) rowptr[i] = boff[blockIdx.x] + sh[t] - v;
  if (i == NN - 1) rowptr[NN] = boff[blockIdx.x] + sh[t];
}
__global__ void k_fill_csr(const int* __restrict__ src, const int* __restrict__ dst,
                           const float* __restrict__ dinv, const int* __restrict__ rowptr,
                           int* cursor, int* __restrict__ csr_src, float* __restrict__ csr_norm) {
  int e = blockIdx.x * blockDim.x + threadIdx.x;
  if (e >= NE) return;
  int s = src[e], d = dst[e];
  int pos = rowptr[d] + atomicAdd(&cursor[d], 1);
  csr_src[pos] = s;
  csr_norm[pos] = dinv[s] * dinv[d];
}

// ---------------- bf16-gather propagation, bf16 out, no base (conv layers) ----------------
__global__ __launch_bounds__(256) void k_prop_bb(const unsigned short* __restrict__ hb,
    unsigned short* __restrict__ outb,
    const int* __restrict__ rowptr, const int* __restrict__ csr_src,
    const float* __restrict__ csr_norm, const float* __restrict__ dinv) {
  int lane = threadIdx.x & 31;
  int d = blockIdx.x * 8 + (threadIdx.x >> 5);
  const uint2* h2 = (const uint2*)hb;
  float dv = dinv[d];
  size_t drow = (size_t)d * 32 + lane;
  float4 v = b4_to_f4(h2[drow]);
  float w = dv * dv;
  float4 acc = make_float4(w * v.x, w * v.y, w * v.z, w * v.w);
  int e = rowptr[d], e1 = rowptr[d + 1];
  for (; e + 7 < e1; e += 8) {
    int   si[8]; float nm[8]; uint2 g[8];
#pragma unroll
    for (int u = 0; u < 8; u++) { si[u] = csr_src[e + u]; nm[u] = csr_norm[e + u]; }
#pragma unroll
    for (int u = 0; u < 8; u++) g[u] = h2[(size_t)si[u] * 32 + lane];
#pragma unroll
    for (int u = 0; u < 8; u++) {
      float4 f = b4_to_f4(g[u]);
      acc.x += nm[u] * f.x; acc.y += nm[u] * f.y;
      acc.z += nm[u] * f.z; acc.w += nm[u] * f.w;
    }
  }
  if (e + 3 < e1) {
    int   si[4]; float nm[4]; uint2 g[4];
#pragma unroll
    for (int u = 0; u < 4; u++) { si[u] = csr_src[e + u]; nm[u] = csr_norm[e + u]; }
#pragma unroll
    for (int u = 0; u < 4; u++) g[u] = h2[(size_t)si[u] * 32 + lane];
#pragma unroll
    for (int u = 0; u < 4; u++) {
      float4 f = b4_to_f4(g[u]);
      acc.x += nm[u] * f.x; acc.y += nm[u] * f.y;
      acc.z += nm[u] * f.z; acc.w += nm[u] * f.w;
    }
    e += 4;
  }
  for (; e < e1; e++) {
    int s = csr_src[e];
    float nn = csr_norm[e];
    float4 f = b4_to_f4(h2[(size_t)s * 32 + lane]);
    acc.x += nn * f.x; acc.y += nn * f.y; acc.z += nn * f.z; acc.w += nn * f.w;
  }
  ((uint2*)outb)[drow] = f4_to_b4(acc);
}

// ---------------- bf16-gather APPNP propagation ----------------
__global__ __launch_bounds__(256) void k_prop_b(const unsigned short* __restrict__ hb,
    const float* __restrict__ base, unsigned short* __restrict__ outb,
    float* __restrict__ outf,
    const int* __restrict__ rowptr, const int* __restrict__ csr_src,
    const float* __restrict__ csr_norm, const float* __restrict__ dinv) {
  int lane = threadIdx.x & 31;
  int d = blockIdx.x * 8 + (threadIdx.x >> 5);
  const uint2* h2 = (const uint2*)hb;
  float dv = dinv[d];
  size_t drow = (size_t)d * 32 + lane;
  float4 v = b4_to_f4(h2[drow]);
  float w = dv * dv;
  float4 acc = make_float4(w * v.x, w * v.y, w * v.z, w * v.w);
  int e = rowptr[d], e1 = rowptr[d + 1];
  for (; e + 7 < e1; e += 8) {
    int   si[8]; float nm[8]; uint2 g[8];
#pragma unroll
    for (int u = 0; u < 8; u++) { si[u] = csr_src[e + u]; nm[u] = csr_norm[e + u]; }
#pragma unroll
    for (int u = 0; u < 8; u++) g[u] = h2[(size_t)si[u] * 32 + lane];
#pragma unroll
    for (int u = 0; u < 8; u++) {
      float4 f = b4_to_f4(g[u]);
      acc.x += nm[u] * f.x; acc.y += nm[u] * f.y;
      acc.z += nm[u] * f.z; acc.w += nm[u] * f.w;
    }
  }
  if (e + 3 < e1) {
    int   si[4]; float nm[4]; uint2 g[4];
#pragma unroll
    for (int u = 0; u < 4; u++) { si[u] = csr_src[e + u]; nm[u] = csr_norm[e + u]; }
#pragma unroll
    for (int u = 0; u < 4; u++) g[u] = h2[(size_t)si[u] * 32 + lane];
#pragma unroll
    for (int u = 0; u < 4; u++) {
      float4 f = b4_to_f4(g[u]);
      acc.x += nm[u] * f.x; acc.y += nm[u] * f.y;
      acc.z += nm[u] * f.z; acc.w += nm[u] * f.w;
    }
    e += 4;
  }
  for (; e < e1; e++) {
    int s = csr_src[e];
    float nn = csr_norm[e];
    float4 f = b4_to_f4(h2[(size_t)s * 32 + lane]);
    acc.x += nn * f.x; acc.y += nn * f.y; acc.z += nn * f.z; acc.w += nn * f.w;
  }
  float4 bb = ((const float4*)base)[drow];
  float4 r;
  r.x = 0.2f * acc.x + 0.8f * bb.x;
  r.y = 0.2f * acc.y + 0.8f * bb.y;
  r.z = 0.2f * acc.z + 0.8f * bb.z;
  r.w = 0.2f * acc.w + 0.8f * bb.w;
  if (outb) {
    ((uint2*)outb)[drow] = f4_to_b4(r);
  } else {
    ((float4*)outf)[drow] = r;
  }
}

// ---------------- MFMA node matmul, coalesced LDS-transpose epilogue + partial stats ----------------
// Y[NN x 128] = A(bf16) @ W + bias. Per-block stats -> pstat[blk*256 + {0..127 sum,128..255 sq}]
__global__ __launch_bounds__(256) void k_mm_mfma(const unsigned short* __restrict__ A,
    const unsigned short* __restrict__ WT, const float* __restrict__ bias,
    float* __restrict__ Y, float* __restrict__ pstat) {
  __shared__ float yt[32][132];   // 132 stride: 16B-aligned rows, 2-way bank alias (free)
  __shared__ float ps[4][H];
  __shared__ float pq[4][H];
  int t = threadIdx.x;
  int lane = t & 63;
  int w = t >> 6;
  int wm = w & 1, wn = w >> 1;
  int rblk = blockIdx.x * 32;
  int rbase = rblk + wm * 16;
  int col0 = wn * 64;
  int l15 = lane & 15;
  int quad = lane >> 4;

  f32x4 acc[4];
#pragma unroll
  for (int tt = 0; tt < 4; tt++) {
    float bb = bias[col0 + 16 * tt + l15];
    acc[tt][0] = bb; acc[tt][1] = bb; acc[tt][2] = bb; acc[tt][3] = bb;
  }
  int arow = rbase + l15; if (arow >= NN) arow = NN - 1;
  const bf16x8* Arow = (const bf16x8*)(A + (size_t)arow * H);
  const bf16x8* B0 = (const bf16x8*)(WT + (size_t)(col0 + l15) * H);
  const bf16x8* B1 = (const bf16x8*)(WT + (size_t)(col0 + 16 + l15) * H);
  const bf16x8* B2 = (const bf16x8*)(WT + (size_t)(col0 + 32 + l15) * H);
  const bf16x8* B3 = (const bf16x8*)(WT + (size_t)(col0 + 48 + l15) * H);
#pragma unroll
  for (int k0 = 0; k0 < 4; k0++) {
    bf16x8 a = Arow[k0 * 4 + quad];
    acc[0] = __builtin_amdgcn_mfma_f32_16x16x32_bf16(a, B0[k0 * 4 + quad], acc[0], 0, 0, 0);
    acc[1] = __builtin_amdgcn_mfma_f32_16x16x32_bf16(a, B1[k0 * 4 + quad], acc[1], 0, 0, 0);
    acc[2] = __builtin_amdgcn_mfma_f32_16x16x32_bf16(a, B2[k0 * 4 + quad], acc[2], 0, 0, 0);
    acc[3] = __builtin_amdgcn_mfma_f32_16x16x32_bf16(a, B3[k0 * 4 + quad], acc[3], 0, 0, 0);
  }
  // C/D layout: col = lane&15, row = quad*4 + reg  -> stage into LDS
#pragma unroll
  for (int tt = 0; tt < 4; tt++) {
    int col = col0 + 16 * tt + l15;
#pragma unroll
    for (int r = 0; r < 4; r++) {
      yt[wm * 16 + quad * 4 + r][col] = acc[tt][r];
    }
  }
  __syncthreads();
  // coalesced float4 row stores + stats
  int c4 = t & 31;
  float s0 = 0.f, s1 = 0.f, s2 = 0.f, s3 = 0.f;
  float q0 = 0.f, q1 = 0.f, q2 = 0.f, q3 = 0.f;
#pragma unroll
  for (int i = 0; i < 4; i++) {
    int idx = t + i * 256;
    int row = idx >> 5;
    float4 v = *(const float4*)&yt[row][c4 * 4];
    int gr = rblk + row;
    if (gr < NN) {
      *(float4*)&Y[(size_t)gr * H + c4 * 4] = v;
      s0 += v.x; s1 += v.y; s2 += v.z; s3 += v.w;
      q0 += v.x * v.x; q1 += v.y * v.y; q2 += v.z * v.z; q3 += v.w * v.w;
    }
  }
  s0 += __shfl_down(s0, 32, 64); s1 += __shfl_down(s1, 32, 64);
  s2 += __shfl_down(s2, 32, 64); s3 += __shfl_down(s3, 32, 64);
  q0 += __shfl_down(q0, 32, 64); q1 += __shfl_down(q1, 32, 64);
  q2 += __shfl_down(q2, 32, 64); q3 += __shfl_down(q3, 32, 64);
  if (lane < 32) {
    ps[w][c4 * 4 + 0] = s0; ps[w][c4 * 4 + 1] = s1;
    ps[w][c4 * 4 + 2] = s2; ps[w][c4 * 4 + 3] = s3;
    pq[w][c4 * 4 + 0] = q0; pq[w][c4 * 4 + 1] = q1;
    pq[w][c4 * 4 + 2] = q2; pq[w][c4 * 4 + 3] = q3;
  }
  __syncthreads();
  if (t < H) {
    pstat[(size_t)blockIdx.x * 256 + t] = ps[0][t] + ps[1][t] + ps[2][t] + ps[3][t];
    pstat[(size_t)blockIdx.x * 256 + 128 + t] = pq[0][t] + pq[1][t] + pq[2][t] + pq[3][t];
  }
}

// reduce per-block partials into gstats (gstats pre-zeroed)
__global__ void k_redstats(const float* __restrict__ pstat, float* __restrict__ gstats) {
  int t = threadIdx.x;  // 256
  float s = 0.f;
  for (int b = blockIdx.x; b < MMB; b += 32) s += pstat[(size_t)b * 256 + t];
  atomicAdd(&gstats[t], s);
}

// ---------------- BN+relu+vn add (bf16 out) + segmented vt scatter ----------------
__global__ void k_bn_vn2(const float* __restrict__ X, const float* __restrict__ stats,
                         const float* __restrict__ g, const float* __restrict__ bt,
                         const float* __restrict__ vn, const int* __restrict__ batch,
                         unsigned short* __restrict__ outb, float* __restrict__ vtsum) {
  int c = threadIdx.x;
  int r0 = blockIdx.x * 16;
  int r1 = r0 + 16; if (r1 > NN) r1 = NN;
  const float invN = 1.0f / NN;
  float m = stats[c] * invN;
  float var = stats[H + c] * invN - m * m;
  float rs = rsqrtf(var + EPSV);
  float gc = g[c], bc = bt[c];
  int curb = batch[r0];
  float vnv = vn[curb * H + c];
  float s = 0.f;
  for (int r = r0; r < r1; r++) {
    int b = batch[r];
    if (b != curb) {
      atomicAdd(&vtsum[curb * H + c], s);
      s = 0.f; curb = b; vnv = vn[b * H + c];
    }
    float y = fmaxf(gc * (X[(size_t)r * H + c] - m) * rs + bc, 0.f) + vnv;
    outb[(size_t)r * H + c] = f2b(y);
    s += y;
  }
  atomicAdd(&vtsum[curb * H + c], s);
}
// BN only: fp32 out (APPNP base) + bf16 out (APPNP iterate)
__global__ void k_bn_plain_b(const float* __restrict__ X, const float* __restrict__ stats,
                             const float* __restrict__ g, const float* __restrict__ bt,
                             float* __restrict__ outf, unsigned short* __restrict__ outb) {
  int idx = blockIdx.x * blockDim.x + threadIdx.x;
  if (idx >= NN * H) return;
  int c = idx & (H - 1);
  const float invN = 1.0f / NN;
  float m = stats[c] * invN;
  float var = stats[H + c] * invN - m * m;
  float rs = rsqrtf(var + EPSV);
  float y = g[c] * (X[idx] - m) * rs + bt[c];
  outf[idx] = y;
  outb[idx] = f2b(y);
}
// BN+relu in place, [NG x C]
__global__ void k_bn_small(float* Y, const float* __restrict__ stats,
                           const float* __restrict__ g, const float* __restrict__ bt,
                           int C) {
  int idx = blockIdx.x * blockDim.x + threadIdx.x;
  if (idx >= NG * C) return;
  int c = idx % C;
  const float invN = 1.0f / NG;
  float m = stats[c] * invN;
  float var = stats[C + c] * invN - m * m;
  float rs = rsqrtf(var + EPSV);
  Y[idx] = fmaxf(g[c] * (Y[idx] - m) * rs + bt[c], 0.f);
}
// BN+relu then vn += result, [NG x 128]
__global__ void k_bn_addvn(const float* __restrict__ Y, const float* __restrict__ stats,
                           const float* __restrict__ g, const float* __restrict__ bt,
                           float* vn) {
  int idx = blockIdx.x * blockDim.x + threadIdx.x;
  if (idx >= NG * H) return;
  int c = idx & (H - 1);
  const float invN = 1.0f / NG;
  float m = stats[c] * invN;
  float var = stats[H + c] * invN - m * m;
  float rs = rsqrtf(var + EPSV);
  vn[idx] += fmaxf(g[c] * (Y[idx] - m) * rs + bt[c], 0.f);
}

// ---------------- small matmuls with fused stats ----------------
__global__ void k_mm_vn1(const float* __restrict__ vtsum, const float* __restrict__ vn,
                         const float* __restrict__ W, const float* __restrict__ bias,
                         float* __restrict__ Y, float* __restrict__ gstats) {
  __shared__ float xs[H];
  int r = blockIdx.x, c = threadIdx.x;
  if (c < H) xs[c] = vtsum[r * H + c] + vn[r * H + c];
  __syncthreads();
  float acc = bias[c];
#pragma unroll 16
  for (int k = 0; k < H; k++) acc += xs[k] * W[k * 256 + c];
  Y[r * 256 + c] = acc;
  atomicAdd(&gstats[c], acc);
  atomicAdd(&gstats[256 + c], acc * acc);
}
__global__ void k_mm_vn2(const float* __restrict__ X, const float* __restrict__ W,
                         const float* __restrict__ bias, float* __restrict__ Y,
                         float* __restrict__ gstats) {
  __shared__ float xs[256];
  int r = blockIdx.x, c = threadIdx.x;
  xs[c] = X[r * 256 + c];
  xs[c + 128] = X[r * 256 + c + 128];
  __syncthreads();
  float acc = bias[c];
#pragma unroll 16
  for (int k = 0; k < 256; k++) acc += xs[k] * W[k * H + c];
  Y[r * H + c] = acc;
  atomicAdd(&gstats[c], acc);
  atomicAdd(&gstats[H + c], acc * acc);
}

// ---------------- segmented pooling (batch sorted) ----------------
__global__ void k_pool2(const float* __restrict__ h, const int* __restrict__ batch,
                        float* pooled) {
  int c = threadIdx.x;
  int r0 = blockIdx.x * 16;
  int r1 = r0 + 16; if (r1 > NN) r1 = NN;
  int curb = batch[r0];
  float s = 0.f;
  for (int r = r0; r < r1; r++) {
    int b = batch[r];
    if (b != curb) { atomicAdd(&pooled[curb * H + c], s); s = 0.f; curb = b; }
    s += h[(size_t)r * H + c];
  }
  atomicAdd(&pooled[curb * H + c], s);
}
__global__ void k_head(const float* __restrict__ pooled, const int* __restrict__ gcnt,
                       const float* __restrict__ Wout, const float* __restrict__ bout,
                       float* __restrict__ out) {
  __shared__ float xs[H];
  int r = blockIdx.x, c = threadIdx.x;
  float inv = 1.0f / fmaxf((float)gcnt[r], 1.0f);
  if (c < H) xs[c] = pooled[r * H + c] * inv;
  __syncthreads();
  float acc = bout[c];
#pragma unroll 16
  for (int k = 0; k < H; k++) acc += xs[k] * Wout[k * OUTC + c];
  out[r * OUTC + c] = acc;
}

// ---------------- launch ----------------
extern "C" void kernel_launch(void* const* d_in, const int* in_sizes, int n_in,
                              void* d_out, int out_size, void* d_ws, size_t ws_size,
                              hipStream_t stream) {
  const float* x      = (const float*)d_in[0];
  const int*   ei     = (const int*)d_in[1];
  const int*   e_src  = ei;
  const int*   e_dst  = ei + NE;
  const int*   batch  = (const int*)d_in[2];
  const float* W      = (const float*)d_in[3];
  const float* b      = (const float*)d_in[4];
  const float* gamma  = (const float*)d_in[5];
  const float* beta   = (const float*)d_in[6];
  const float* vn_emb = (const float*)d_in[7];
  const float* W1     = (const float*)d_in[8];
  const float* b1     = (const float*)d_in[9];
  const float* g1     = (const float*)d_in[10];
  const float* bt1    = (const float*)d_in[11];
  const float* W2     = (const float*)d_in[12];
  const float* b2     = (const float*)d_in[13];
  const float* g2     = (const float*)d_in[14];
  const float* bt2    = (const float*)d_in[15];
  const float* Wout   = (const float*)d_in[16];
  const float* bout   = (const float*)d_in[17];
  float* out = (float*)d_out;

  char* p = (char*)d_ws;
  auto alloc = [&](size_t bytes) -> char* {
    char* r = p; p += (bytes + 255) & ~(size_t)255; return r;
  };
  float* hA       = (float*)alloc((size_t)NN * H * 4);
  float* hB       = (float*)alloc((size_t)NN * H * 4);   // carved into bf0/bf1
  float* hC       = (float*)alloc((size_t)NN * H * 4);
  int*   deg      = (int*)alloc((size_t)NN * 4);
  int*   cursor   = (int*)alloc((size_t)NN * 4);
  int*   rowptr   = (int*)alloc((size_t)(NN + 1) * 4);
  int*   gcnt     = (int*)alloc(512 * 4);
  int*   csr_src  = (int*)alloc((size_t)NE * 4);
  float* csr_norm = (float*)alloc((size_t)NE * 4);
  float* dinv     = (float*)alloc((size_t)NN * 4);
  float* vn       = (float*)alloc((size_t)NG * H * 4);
  float* vtsum0   = (float*)alloc((size_t)NG * H * 4);
  float* vtsum1   = (float*)alloc((size_t)NG * H * 4);
  float* t1       = (float*)alloc((size_t)NG * 256 * 4);
  float* t2       = (float*)alloc((size_t)NG * H * 4);
  float* pooled   = (float*)alloc((size_t)NG * H * 4);
  float* stats    = (float*)alloc(9 * 512 * 4);
  int*   bsum     = (int*)alloc(256 * 4);
  int*   boff     = (int*)alloc(256 * 4);
  unsigned short* WT = (unsigned short*)alloc((size_t)3 * H * H * 2);
  unsigned short* xb = (unsigned short*)alloc((size_t)NN * H * 2);
  float* pstat    = (float*)alloc((size_t)MMB * 256 * 4);

  unsigned short* bf0 = (unsigned short*)hB;
  unsigned short* bf1 = (unsigned short*)hB + (size_t)NN * H;

  const int B = 256;
  const int gNN   = (NN + B - 1) / B;
  const int gNE   = (NE + B - 1) / B;
  const int gELT  = (NN * H + B - 1) / B;
  const int gVN   = (NG * H + B - 1) / B;
  const int gSEG  = (NN + 15) / 16;            // 3125
  const int gPROP = NN / 8;                    // 6250

  // ---- init + conversions + graph preprocessing ----
  k_init<<<(NG * H + B - 1) / B, B, 0, stream>>>(deg, cursor, gcnt, stats, vtsum0, vtsum1,
                                                 pooled, vn_emb, vn);
  k_wconv<<<(3 * H * H + B - 1) / B, B, 0, stream>>>(W, WT);
  k_xconv<<<(NN * H / 4 + B - 1) / B, B, 0, stream>>>(x, xb);
  k_hist_edges<<<gNE, B, 0, stream>>>(e_dst, deg);
  k_hist_batch<<<gNN, B, 0, stream>>>(batch, gcnt);
  k_dinv<<<gNN, B, 0, stream>>>(deg, dinv);
  k_scan1<<<NB1, 256, 0, stream>>>(deg, bsum);
  k_scan2<<<1, 256, 0, stream>>>(bsum, boff);
  k_scan3<<<NB1, 256, 0, stream>>>(deg, boff, rowptr);
  k_fill_csr<<<gNE, B, 0, stream>>>(e_src, e_dst, dinv, rowptr, cursor, csr_src, csr_norm);

  float* st[7];
  for (int i = 0; i < 7; i++) st[i] = stats + i * 512;

  // ---- conv layers 0,1 with virtual node MLP ----
  const unsigned short* curb = xb;
  float* vts[2] = {vtsum0, vtsum1};
  for (int i = 0; i < 2; i++) {
    int j = (i == 0) ? 1 : 0;
    k_prop_bb<<<gPROP, 256, 0, stream>>>(curb, bf0, rowptr, csr_src, csr_norm, dinv);
    k_mm_mfma<<<MMB, 256, 0, stream>>>(bf0, WT + (size_t)i * H * H, b + i * H, hC, pstat);
    k_redstats<<<32, 256, 0, stream>>>(pstat, st[3 * i]);
    k_bn_vn2<<<gSEG, H, 0, stream>>>(hC, st[3 * i], gamma + i * H, beta + i * H, vn, batch, bf1, vts[i]);
    k_mm_vn1<<<NG, 256, 0, stream>>>(vts[i], vn, W1 + (size_t)j * H * 256, b1 + j * 256, t1, st[3 * i + 1]);
    k_bn_small<<<(NG * 256 + B - 1) / B, B, 0, stream>>>(t1, st[3 * i + 1], g1 + j * 256, bt1 + j * 256, 256);
    k_mm_vn2<<<NG, 128, 0, stream>>>(t1, W2 + (size_t)j * 256 * H, b2 + j * H, t2, st[3 * i + 2]);
    k_bn_addvn<<<gVN, B, 0, stream>>>(t2, st[3 * i + 2], g2 + j * H, bt2 + j * H, vn);
    curb = bf1;
  }

  // ---- last conv layer ----
  k_prop_bb<<<gPROP, 256, 0, stream>>>(bf1, bf0, rowptr, csr_src, csr_norm, dinv);
  k_mm_mfma<<<MMB, 256, 0, stream>>>(bf0, WT + (size_t)2 * H * H, b + 2 * H, hC, pstat);
  k_redstats<<<32, 256, 0, stream>>>(pstat, st[6]);
  k_bn_plain_b<<<gELT, B, 0, stream>>>(hC, st[6], gamma + 2 * H, beta + 2 * H, hA, bf0);

  // ---- APPNP: h0 = hA (fp32), iterate bf16, final -> hC (fp32) ----
  k_prop_b<<<gPROP, 256, 0, stream>>>(bf0, hA, bf1, nullptr, rowptr, csr_src, csr_norm, dinv);
  k_prop_b<<<gPROP, 256, 0, stream>>>(bf1, hA, bf0, nullptr, rowptr, csr_src, csr_norm, dinv);
  k_prop_b<<<gPROP, 256, 0, stream>>>(bf0, hA, bf1, nullptr, rowptr, csr_src, csr_norm, dinv);
  k_prop_b<<<gPROP, 256, 0, stream>>>(bf1, hA, bf0, nullptr, rowptr, csr_src, csr_norm, dinv);
  k_prop_b<<<gPROP, 256, 0, stream>>>(bf0, hA, nullptr, hC, rowptr, csr_src, csr_norm, dinv);

  // ---- mean pool + head ----
  k_pool2<<<gSEG, H, 0, stream>>>(hC, batch, pooled);
  k_head<<<NG, OUTC, 0, stream>>>(pooled, gcnt, Wout, bout, out);
}

// Round 7
// 648.581 us; speedup vs baseline: 2.0764x; 1.0202x over previous
//
#include <hip/hip_runtime.h>
#include <cstddef>
#include <cstdint>

#define NN 50000
#define NE 600000
#define H 128
#define NG 512
#define OUTC 128
#define EPSV 1e-5f
#define NB1 196   // ceil(NN/256)
#define MMB 1563  // ceil(NN/32)

typedef __attribute__((ext_vector_type(8))) short bf16x8;
typedef __attribute__((ext_vector_type(4))) float f32x4;

__device__ __forceinline__ unsigned short f2b(float f) {
  uint32_t u = __float_as_uint(f);
  uint32_t r = u + 0x7FFFu + ((u >> 16) & 1u);
  return (unsigned short)(r >> 16);
}
__device__ __forceinline__ float4 b4_to_f4(uint2 v) {
  float4 f;
  f.x = __uint_as_float(v.x << 16);
  f.y = __uint_as_float(v.x & 0xFFFF0000u);
  f.z = __uint_as_float(v.y << 16);
  f.w = __uint_as_float(v.y & 0xFFFF0000u);
  return f;
}
__device__ __forceinline__ uint2 f4_to_b4(float4 r) {
  uint2 o;
  o.x = (uint32_t)f2b(r.x) | ((uint32_t)f2b(r.y) << 16);
  o.y = (uint32_t)f2b(r.z) | ((uint32_t)f2b(r.w) << 16);
  return o;
}

// ---------------- combined init (+ W->bf16 W^T) ----------------
__global__ void k_init(int* deg, int* cursor, int* gcnt, float* stats,
                       float* vtsum0, float* vtsum1, float* pooled,
                       const float* __restrict__ vn_emb, float* vn,
                       const float* __restrict__ W, unsigned short* __restrict__ WT) {
  int i = blockIdx.x * blockDim.x + threadIdx.x;
  if (i < NN) { deg[i] = 1; cursor[i] = 0; }
  if (i < NG) gcnt[i] = 0;
  if (i < 9 * 512) stats[i] = 0.f;
  if (i < 3 * H * H) {
    int l = i >> 14;
    int rem = i & 16383;
    int n = rem >> 7, k = rem & 127;
    WT[i] = f2b(W[l * H * H + k * H + n]);
  }
  if (i < NG * H) {
    vtsum0[i] = 0.f; vtsum1[i] = 0.f; pooled[i] = 0.f;
    vn[i] = vn_emb[i & (H - 1)];
  }
}

// x -> u0 = dinv * x (bf16)
__global__ void k_xconv(const float* __restrict__ x, const float* __restrict__ dinv,
                        unsigned short* __restrict__ xb) {
  int i = blockIdx.x * blockDim.x + threadIdx.x;
  if (i >= NN * H / 4) return;
  float dv = dinv[i >> 5];
  float4 v = ((const float4*)x)[i];
  v.x *= dv; v.y *= dv; v.z *= dv; v.w *= dv;
  ((uint2*)xb)[i] = f4_to_b4(v);
}

// ---------------- graph preprocessing ----------------
__global__ void k_hist(const int* __restrict__ dst, int* deg,
                       const int* __restrict__ batch, int* gcnt) {
  int e = blockIdx.x * blockDim.x + threadIdx.x;
  if (e < NE) atomicAdd(&deg[dst[e]], 1);
  if (e < NN) atomicAdd(&gcnt[batch[e]], 1);
}
__global__ void k_dinv(const int* __restrict__ deg, float* dinv) {
  int i = blockIdx.x * blockDim.x + threadIdx.x;
  if (i < NN) dinv[i] = rsqrtf((float)deg[i]);
}
__global__ void k_scan1(const int* __restrict__ deg, int* bsum) {
  __shared__ int sh[256];
  int t = threadIdx.x;
  int i = blockIdx.x * 256 + t;
  sh[t] = (i < NN) ? deg[i] - 1 : 0;
  __syncthreads();
  for (int o = 128; o > 0; o >>= 1) {
    if (t < o) sh[t] += sh[t + o];
    __syncthreads();
  }
  if (t == 0) bsum[blockIdx.x] = sh[0];
}
__global__ void k_scan2(const int* __restrict__ bsum, int* boff) {
  __shared__ int sh[256];
  int t = threadIdx.x;
  int v = (t < NB1) ? bsum[t] : 0;
  sh[t] = v;
  __syncthreads();
  for (int o = 1; o < 256; o <<= 1) {
    int u = (t >= o) ? sh[t - o] : 0;
    __syncthreads();
    sh[t] += u;
    __syncthreads();
  }
  if (t < NB1) boff[t] = sh[t] - v;
}
__global__ void k_scan3(const int* __restrict__ deg, const int* __restrict__ boff,
                        int* __restrict__ rowptr) {
  __shared__ int sh[256];
  int t = threadIdx.x;
  int i = blockIdx.x * 256 + t;
  int v = (i < NN) ? deg[i] - 1 : 0;
  sh[t] = v;
  __syncthreads();
  for (int o = 1; o < 256; o <<= 1) {
    int u = (t >= o) ? sh[t - o] : 0;
    __syncthreads();
    sh[t] += u;
    __syncthreads();
  }
  if (i < NN) rowptr[i] = boff[blockIdx.x] + sh[t] - v;
  if (i == NN - 1) rowptr[NN] = boff[blockIdx.x] + sh[t];
}
__global__ void k_fill_csr(const int* __restrict__ src, const int* __restrict__ dst,
                           const int* __restrict__ rowptr, int* cursor,
                           int* __restrict__ csr_src) {
  int e = blockIdx.x * blockDim.x + threadIdx.x;
  if (e >= NE) return;
  int s = src[e], d = dst[e];
  int pos = rowptr[d] + atomicAdd(&cursor[d], 1);
  csr_src[pos] = s;
}

// ---------------- fused conv: u-space SpMM gather -> LDS -> MFMA matmul + stats ----------------
// U: u-space bf16 [NN][128]. Y = (A_hat h) @ W + bias, where h = D^{1/2} u.
__global__ __launch_bounds__(256) void k_prop_mm(const unsigned short* __restrict__ U,
    const unsigned short* __restrict__ WT, const float* __restrict__ bias,
    float* __restrict__ Y, float* __restrict__ pstat,
    const int* __restrict__ rowptr, const int* __restrict__ csr_src,
    const float* __restrict__ dinv) {
  __shared__ unsigned short abuf[32][136];  // padded: stride 272B -> bank offset 4/row
  __shared__ float yt[32][132];
  __shared__ float ps[4][H], pq[4][H];
  int t = threadIdx.x;
  int lane32 = t & 31;
  int g = t >> 5;   // 0..7
  int rblk = blockIdx.x * 32;
  const uint2* u2 = (const uint2*)U;

  // phase 1: gather 4 rows per 32-lane group (h-space result, bf16 into LDS)
  for (int rr = 0; rr < 4; rr++) {
    int d = rblk + g * 4 + rr;
    float4 acc = make_float4(0.f, 0.f, 0.f, 0.f);
    float dv = 0.f;
    if (d < NN) {
      dv = dinv[d];
      acc = b4_to_f4(u2[(size_t)d * 32 + lane32]);   // self term u[d]
      int e = rowptr[d], e1 = rowptr[d + 1];
      for (; e + 7 < e1; e += 8) {
        int si[8]; uint2 gg[8];
#pragma unroll
        for (int u = 0; u < 8; u++) si[u] = csr_src[e + u];
#pragma unroll
        for (int u = 0; u < 8; u++) gg[u] = u2[(size_t)si[u] * 32 + lane32];
#pragma unroll
        for (int u = 0; u < 8; u++) {
          float4 f = b4_to_f4(gg[u]);
          acc.x += f.x; acc.y += f.y; acc.z += f.z; acc.w += f.w;
        }
      }
      if (e + 3 < e1) {
        int si[4]; uint2 gg[4];
#pragma unroll
        for (int u = 0; u < 4; u++) si[u] = csr_src[e + u];
#pragma unroll
        for (int u = 0; u < 4; u++) gg[u] = u2[(size_t)si[u] * 32 + lane32];
#pragma unroll
        for (int u = 0; u < 4; u++) {
          float4 f = b4_to_f4(gg[u]);
          acc.x += f.x; acc.y += f.y; acc.z += f.z; acc.w += f.w;
        }
        e += 4;
      }
      for (; e < e1; e++) {
        float4 f = b4_to_f4(u2[(size_t)csr_src[e] * 32 + lane32]);
        acc.x += f.x; acc.y += f.y; acc.z += f.z; acc.w += f.w;
      }
    }
    acc.x *= dv; acc.y *= dv; acc.z *= dv; acc.w *= dv;  // back to h-space
    *(uint2*)&abuf[g * 4 + rr][lane32 * 4] = f4_to_b4(acc);
  }
  __syncthreads();

  // phase 2: MFMA (A from LDS, B=W^T from global/L2)
  int lane = t & 63;
  int w = t >> 6;
  int wm = w & 1, wn = w >> 1;
  int rbase = rblk + wm * 16;
  int col0 = wn * 64;
  int l15 = lane & 15;
  int quad = lane >> 4;
  f32x4 acc[4];
#pragma unroll
  for (int tt = 0; tt < 4; tt++) {
    float bb = bias[col0 + 16 * tt + l15];
    acc[tt][0] = bb; acc[tt][1] = bb; acc[tt][2] = bb; acc[tt][3] = bb;
  }
  const bf16x8* B0 = (const bf16x8*)(WT + (size_t)(col0 + l15) * H);
  const bf16x8* B1 = (const bf16x8*)(WT + (size_t)(col0 + 16 + l15) * H);
  const bf16x8* B2 = (const bf16x8*)(WT + (size_t)(col0 + 32 + l15) * H);
  const bf16x8* B3 = (const bf16x8*)(WT + (size_t)(col0 + 48 + l15) * H);
#pragma unroll
  for (int k0 = 0; k0 < 4; k0++) {
    bf16x8 a = *(const bf16x8*)&abuf[wm * 16 + l15][k0 * 32 + quad * 8];
    acc[0] = __builtin_amdgcn_mfma_f32_16x16x32_bf16(a, B0[k0 * 4 + quad], acc[0], 0, 0, 0);
    acc[1] = __builtin_amdgcn_mfma_f32_16x16x32_bf16(a, B1[k0 * 4 + quad], acc[1], 0, 0, 0);
    acc[2] = __builtin_amdgcn_mfma_f32_16x16x32_bf16(a, B2[k0 * 4 + quad], acc[2], 0, 0, 0);
    acc[3] = __builtin_amdgcn_mfma_f32_16x16x32_bf16(a, B3[k0 * 4 + quad], acc[3], 0, 0, 0);
  }
  __syncthreads();
  // C/D: col = lane&15, row = quad*4+reg -> stage to LDS
#pragma unroll
  for (int tt = 0; tt < 4; tt++) {
    int col = col0 + 16 * tt + l15;
#pragma unroll
    for (int r = 0; r < 4; r++) {
      yt[wm * 16 + quad * 4 + r][col] = acc[tt][r];
    }
  }
  __syncthreads();
  // coalesced float4 row stores + per-block stats partials
  int c4 = t & 31;
  float s0 = 0.f, s1 = 0.f, s2 = 0.f, s3 = 0.f;
  float q0 = 0.f, q1 = 0.f, q2 = 0.f, q3 = 0.f;
#pragma unroll
  for (int i = 0; i < 4; i++) {
    int idx = t + i * 256;
    int row = idx >> 5;
    float4 v = *(const float4*)&yt[row][c4 * 4];
    int gr = rblk + row;
    if (gr < NN) {
      *(float4*)&Y[(size_t)gr * H + c4 * 4] = v;
      s0 += v.x; s1 += v.y; s2 += v.z; s3 += v.w;
      q0 += v.x * v.x; q1 += v.y * v.y; q2 += v.z * v.z; q3 += v.w * v.w;
    }
  }
  s0 += __shfl_down(s0, 32, 64); s1 += __shfl_down(s1, 32, 64);
  s2 += __shfl_down(s2, 32, 64); s3 += __shfl_down(s3, 32, 64);
  q0 += __shfl_down(q0, 32, 64); q1 += __shfl_down(q1, 32, 64);
  q2 += __shfl_down(q2, 32, 64); q3 += __shfl_down(q3, 32, 64);
  if (lane < 32) {
    ps[w][c4 * 4 + 0] = s0; ps[w][c4 * 4 + 1] = s1;
    ps[w][c4 * 4 + 2] = s2; ps[w][c4 * 4 + 3] = s3;
    pq[w][c4 * 4 + 0] = q0; pq[w][c4 * 4 + 1] = q1;
    pq[w][c4 * 4 + 2] = q2; pq[w][c4 * 4 + 3] = q3;
  }
  __syncthreads();
  if (t < H) {
    pstat[(size_t)blockIdx.x * 256 + t] = ps[0][t] + ps[1][t] + ps[2][t] + ps[3][t];
    pstat[(size_t)blockIdx.x * 256 + 128 + t] = pq[0][t] + pq[1][t] + pq[2][t] + pq[3][t];
  }
}

// reduce per-block partials into gstats (gstats pre-zeroed)
__global__ void k_redstats(const float* __restrict__ pstat, float* __restrict__ gstats) {
  int t = threadIdx.x;
  float s = 0.f;
  for (int b = blockIdx.x; b < MMB; b += 32) s += pstat[(size_t)b * 256 + t];
  atomicAdd(&gstats[t], s);
}

// ---------------- u-space APPNP propagation (bf16 in, bf16 out) ----------------
// h_next = 0.2 * dv * (u[d] + sum u[s]) + 0.8 * base[d]; out = bf16(uspace ? dv*h_next : h_next)
__global__ __launch_bounds__(256) void k_prop_b(const unsigned short* __restrict__ U,
    const float* __restrict__ base, unsigned short* __restrict__ outb, int uspace,
    const int* __restrict__ rowptr, const int* __restrict__ csr_src,
    const float* __restrict__ dinv) {
  int lane = threadIdx.x & 31;
  int d = blockIdx.x * 8 + (threadIdx.x >> 5);
  const uint2* u2 = (const uint2*)U;
  float dv = dinv[d];
  size_t drow = (size_t)d * 32 + lane;
  float4 acc = b4_to_f4(u2[drow]);   // self term
  int e = rowptr[d], e1 = rowptr[d + 1];
  for (; e + 7 < e1; e += 8) {
    int si[8]; uint2 gg[8];
#pragma unroll
    for (int u = 0; u < 8; u++) si[u] = csr_src[e + u];
#pragma unroll
    for (int u = 0; u < 8; u++) gg[u] = u2[(size_t)si[u] * 32 + lane];
#pragma unroll
    for (int u = 0; u < 8; u++) {
      float4 f = b4_to_f4(gg[u]);
      acc.x += f.x; acc.y += f.y; acc.z += f.z; acc.w += f.w;
    }
  }
  if (e + 3 < e1) {
    int si[4]; uint2 gg[4];
#pragma unroll
    for (int u = 0; u < 4; u++) si[u] = csr_src[e + u];
#pragma unroll
    for (int u = 0; u < 4; u++) gg[u] = u2[(size_t)si[u] * 32 + lane];
#pragma unroll
    for (int u = 0; u < 4; u++) {
      float4 f = b4_to_f4(gg[u]);
      acc.x += f.x; acc.y += f.y; acc.z += f.z; acc.w += f.w;
    }
    e += 4;
  }
  for (; e < e1; e++) {
    float4 f = b4_to_f4(u2[(size_t)csr_src[e] * 32 + lane]);
    acc.x += f.x; acc.y += f.y; acc.z += f.z; acc.w += f.w;
  }
  float4 bb = ((const float4*)base)[drow];
  float k = 0.2f * dv;
  float4 h;
  h.x = k * acc.x + 0.8f * bb.x;
  h.y = k * acc.y + 0.8f * bb.y;
  h.z = k * acc.z + 0.8f * bb.z;
  h.w = k * acc.w + 0.8f * bb.w;
  float osc = uspace ? dv : 1.0f;
  h.x *= osc; h.y *= osc; h.z *= osc; h.w *= osc;
  ((uint2*)outb)[drow] = f4_to_b4(h);
}

// ---------------- BN+relu+vn add (u-space bf16 out) + segmented vt scatter ----------------
__global__ void k_bn_vn2(const float* __restrict__ X, const float* __restrict__ stats,
                         const float* __restrict__ g, const float* __restrict__ bt,
                         const float* __restrict__ vn, const int* __restrict__ batch,
                         const float* __restrict__ dinv,
                         unsigned short* __restrict__ outb, float* __restrict__ vtsum) {
  int c = threadIdx.x;
  int r0 = blockIdx.x * 16;
  int r1 = r0 + 16; if (r1 > NN) r1 = NN;
  const float invN = 1.0f / NN;
  float m = stats[c] * invN;
  float var = stats[H + c] * invN - m * m;
  float rs = rsqrtf(var + EPSV);
  float gc = g[c], bc = bt[c];
  int curb = batch[r0];
  float vnv = vn[curb * H + c];
  float s = 0.f;
  for (int r = r0; r < r1; r++) {
    int b = batch[r];
    if (b != curb) {
      atomicAdd(&vtsum[curb * H + c], s);
      s = 0.f; curb = b; vnv = vn[b * H + c];
    }
    float y = fmaxf(gc * (X[(size_t)r * H + c] - m) * rs + bc, 0.f) + vnv;
    outb[(size_t)r * H + c] = f2b(dinv[r] * y);   // u-space for next prop
    s += y;                                        // h-space for vt
  }
  atomicAdd(&vtsum[curb * H + c], s);
}
// BN only: h0 fp32 (APPNP base) + u0 bf16 (APPNP iterate)
__global__ void k_bn_plain_b(const float* __restrict__ X, const float* __restrict__ stats,
                             const float* __restrict__ g, const float* __restrict__ bt,
                             const float* __restrict__ dinv,
                             float* __restrict__ outf, unsigned short* __restrict__ outb) {
  int idx = blockIdx.x * blockDim.x + threadIdx.x;
  if (idx >= NN * H) return;
  int c = idx & (H - 1);
  const float invN = 1.0f / NN;
  float m = stats[c] * invN;
  float var = stats[H + c] * invN - m * m;
  float rs = rsqrtf(var + EPSV);
  float y = g[c] * (X[idx] - m) * rs + bt[c];
  outf[idx] = y;
  outb[idx] = f2b(dinv[idx >> 7] * y);
}
// BN+relu in place, [NG x C]
__global__ void k_bn_small(float* Y, const float* __restrict__ stats,
                           const float* __restrict__ g, const float* __restrict__ bt,
                           int C) {
  int idx = blockIdx.x * blockDim.x + threadIdx.x;
  if (idx >= NG * C) return;
  int c = idx % C;
  const float invN = 1.0f / NG;
  float m = stats[c] * invN;
  float var = stats[C + c] * invN - m * m;
  float rs = rsqrtf(var + EPSV);
  Y[idx] = fmaxf(g[c] * (Y[idx] - m) * rs + bt[c], 0.f);
}
// BN+relu then vn += result, [NG x 128]
__global__ void k_bn_addvn(const float* __restrict__ Y, const float* __restrict__ stats,
                           const float* __restrict__ g, const float* __restrict__ bt,
                           float* vn) {
  int idx = blockIdx.x * blockDim.x + threadIdx.x;
  if (idx >= NG * H) return;
  int c = idx & (H - 1);
  const float invN = 1.0f / NG;
  float m = stats[c] * invN;
  float var = stats[H + c] * invN - m * m;
  float rs = rsqrtf(var + EPSV);
  vn[idx] += fmaxf(g[c] * (Y[idx] - m) * rs + bt[c], 0.f);
}

// ---------------- small matmuls with fused stats ----------------
__global__ void k_mm_vn1(const float* __restrict__ vtsum, const float* __restrict__ vn,
                         const float* __restrict__ W, const float* __restrict__ bias,
                         float* __restrict__ Y, float* __restrict__ gstats) {
  __shared__ float xs[H];
  int r = blockIdx.x, c = threadIdx.x;
  if (c < H) xs[c] = vtsum[r * H + c] + vn[r * H + c];
  __syncthreads();
  float acc = bias[c];
#pragma unroll 16
  for (int k = 0; k < H; k++) acc += xs[k] * W[k * 256 + c];
  Y[r * 256 + c] = acc;
  atomicAdd(&gstats[c], acc);
  atomicAdd(&gstats[256 + c], acc * acc);
}
__global__ void k_mm_vn2(const float* __restrict__ X, const float* __restrict__ W,
                         const float* __restrict__ bias, float* __restrict__ Y,
                         float* __restrict__ gstats) {
  __shared__ float xs[256];
  int r = blockIdx.x, c = threadIdx.x;
  xs[c] = X[r * 256 + c];
  xs[c + 128] = X[r * 256 + c + 128];
  __syncthreads();
  float acc = bias[c];
#pragma unroll 16
  for (int k = 0; k < 256; k++) acc += xs[k] * W[k * H + c];
  Y[r * H + c] = acc;
  atomicAdd(&gstats[c], acc);
  atomicAdd(&gstats[H + c], acc * acc);
}

// ---------------- segmented pooling (batch sorted, bf16 input) ----------------
__global__ void k_pool2(const unsigned short* __restrict__ hb, const int* __restrict__ batch,
                        float* pooled) {
  int c = threadIdx.x;
  int r0 = blockIdx.x * 16;
  int r1 = r0 + 16; if (r1 > NN) r1 = NN;
  int curb = batch[r0];
  float s = 0.f;
  for (int r = r0; r < r1; r++) {
    int b = batch[r];
    if (b != curb) { atomicAdd(&pooled[curb * H + c], s); s = 0.f; curb = b; }
    s += __uint_as_float((uint32_t)hb[(size_t)r * H + c] << 16);
  }
  atomicAdd(&pooled[curb * H + c], s);
}
__global__ void k_head(const float* __restrict__ pooled, const int* __restrict__ gcnt,
                       const float* __restrict__ Wout, const float* __restrict__ bout,
                       float* __restrict__ out) {
  __shared__ float xs[H];
  int r = blockIdx.x, c = threadIdx.x;
  float inv = 1.0f / fmaxf((float)gcnt[r], 1.0f);
  if (c < H) xs[c] = pooled[r * H + c] * inv;
  __syncthreads();
  float acc = bout[c];
#pragma unroll 16
  for (int k = 0; k < H; k++) acc += xs[k] * Wout[k * OUTC + c];
  out[r * OUTC + c] = acc;
}

// ---------------- launch ----------------
extern "C" void kernel_launch(void* const* d_in, const int* in_sizes, int n_in,
                              void* d_out, int out_size, void* d_ws, size_t ws_size,
                              hipStream_t stream) {
  const float* x      = (const float*)d_in[0];
  const int*   ei     = (const int*)d_in[1];
  const int*   e_src  = ei;
  const int*   e_dst  = ei + NE;
  const int*   batch  = (const int*)d_in[2];
  const float* W      = (const float*)d_in[3];
  const float* b      = (const float*)d_in[4];
  const float* gamma  = (const float*)d_in[5];
  const float* beta   = (const float*)d_in[6];
  const float* vn_emb = (const float*)d_in[7];
  const float* W1     = (const float*)d_in[8];
  const float* b1     = (const float*)d_in[9];
  const float* g1     = (const float*)d_in[10];
  const float* bt1    = (const float*)d_in[11];
  const float* W2     = (const float*)d_in[12];
  const float* b2     = (const float*)d_in[13];
  const float* g2     = (const float*)d_in[14];
  const float* bt2    = (const float*)d_in[15];
  const float* Wout   = (const float*)d_in[16];
  const float* bout   = (const float*)d_in[17];
  float* out = (float*)d_out;

  char* p = (char*)d_ws;
  auto alloc = [&](size_t bytes) -> char* {
    char* r = p; p += (bytes + 255) & ~(size_t)255; return r;
  };
  float* hA       = (float*)alloc((size_t)NN * H * 4);
  float* hB       = (float*)alloc((size_t)NN * H * 4);   // carved into bf0/bf1
  float* hC       = (float*)alloc((size_t)NN * H * 4);
  int*   deg      = (int*)alloc((size_t)NN * 4);
  int*   cursor   = (int*)alloc((size_t)NN * 4);
  int*   rowptr   = (int*)alloc((size_t)(NN + 1) * 4);
  int*   gcnt     = (int*)alloc(512 * 4);
  int*   csr_src  = (int*)alloc((size_t)NE * 4);
  float* dinv     = (float*)alloc((size_t)NN * 4);
  float* vn       = (float*)alloc((size_t)NG * H * 4);
  float* vtsum0   = (float*)alloc((size_t)NG * H * 4);
  float* vtsum1   = (float*)alloc((size_t)NG * H * 4);
  float* t1       = (float*)alloc((size_t)NG * 256 * 4);
  float* t2       = (float*)alloc((size_t)NG * H * 4);
  float* pooled   = (float*)alloc((size_t)NG * H * 4);
  float* stats    = (float*)alloc(9 * 512 * 4);
  int*   bsum     = (int*)alloc(256 * 4);
  int*   boff     = (int*)alloc(256 * 4);
  unsigned short* WT = (unsigned short*)alloc((size_t)3 * H * H * 2);
  unsigned short* xb = (unsigned short*)alloc((size_t)NN * H * 2);
  float* pstat    = (float*)alloc((size_t)MMB * 256 * 4);

  unsigned short* bf0 = (unsigned short*)hB;
  unsigned short* bf1 = (unsigned short*)hB + (size_t)NN * H;

  const int B = 256;
  const int gNN   = (NN + B - 1) / B;
  const int gNE   = (NE + B - 1) / B;
  const int gELT  = (NN * H + B - 1) / B;
  const int gVN   = (NG * H + B - 1) / B;
  const int gSEG  = (NN + 15) / 16;            // 3125
  const int gPROP = NN / 8;                    // 6250

  // ---- init + graph preprocessing ----
  k_init<<<(NG * H + B - 1) / B, B, 0, stream>>>(deg, cursor, gcnt, stats, vtsum0, vtsum1,
                                                 pooled, vn_emb, vn, W, WT);
  k_hist<<<gNE, B, 0, stream>>>(e_dst, deg, batch, gcnt);
  k_dinv<<<gNN, B, 0, stream>>>(deg, dinv);
  k_xconv<<<(NN * H / 4 + B - 1) / B, B, 0, stream>>>(x, dinv, xb);
  k_scan1<<<NB1, 256, 0, stream>>>(deg, bsum);
  k_scan2<<<1, 256, 0, stream>>>(bsum, boff);
  k_scan3<<<NB1, 256, 0, stream>>>(deg, boff, rowptr);
  k_fill_csr<<<gNE, B, 0, stream>>>(e_src, e_dst, rowptr, cursor, csr_src);

  float* st[7];
  for (int i = 0; i < 7; i++) st[i] = stats + i * 512;

  // ---- conv layers 0,1 with virtual node MLP ----
  const unsigned short* curb = xb;
  unsigned short* bnout[2] = {bf1, bf0};
  float* vts[2] = {vtsum0, vtsum1};
  for (int i = 0; i < 2; i++) {
    int j = (i == 0) ? 1 : 0;
    k_prop_mm<<<MMB, 256, 0, stream>>>(curb, WT + (size_t)i * H * H, b + i * H, hC, pstat,
                                       rowptr, csr_src, dinv);
    k_redstats<<<32, 256, 0, stream>>>(pstat, st[3 * i]);
    k_bn_vn2<<<gSEG, H, 0, stream>>>(hC, st[3 * i], gamma + i * H, beta + i * H, vn, batch,
                                     dinv, bnout[i], vts[i]);
    k_mm_vn1<<<NG, 256, 0, stream>>>(vts[i], vn, W1 + (size_t)j * H * 256, b1 + j * 256, t1, st[3 * i + 1]);
    k_bn_small<<<(NG * 256 + B - 1) / B, B, 0, stream>>>(t1, st[3 * i + 1], g1 + j * 256, bt1 + j * 256, 256);
    k_mm_vn2<<<NG, 128, 0, stream>>>(t1, W2 + (size_t)j * 256 * H, b2 + j * H, t2, st[3 * i + 2]);
    k_bn_addvn<<<gVN, B, 0, stream>>>(t2, st[3 * i + 2], g2 + j * H, bt2 + j * H, vn);
    curb = bnout[i];
  }

  // ---- last conv layer: fused prop+mm, BN (h0 fp32 hA + u0 bf16 bf1) ----
  k_prop_mm<<<MMB, 256, 0, stream>>>(bf0, WT + (size_t)2 * H * H, b + 2 * H, hC, pstat,
                                     rowptr, csr_src, dinv);
  k_redstats<<<32, 256, 0, stream>>>(pstat, st[6]);
  k_bn_plain_b<<<gELT, B, 0, stream>>>(hC, st[6], gamma + 2 * H, beta + 2 * H, dinv, hA, bf1);

  // ---- APPNP: base hA fp32, iterate u-space bf16, final h-space bf16 -> bf1 ----
  k_prop_b<<<gPROP, 256, 0, stream>>>(bf1, hA, bf0, 1, rowptr, csr_src, dinv);
  k_prop_b<<<gPROP, 256, 0, stream>>>(bf0, hA, bf1, 1, rowptr, csr_src, dinv);
  k_prop_b<<<gPROP, 256, 0, stream>>>(bf1, hA, bf0, 1, rowptr, csr_src, dinv);
  k_prop_b<<<gPROP, 256, 0, stream>>>(bf0, hA, bf1, 1, rowptr, csr_src, dinv);
  k_prop_b<<<gPROP, 256, 0, stream>>>(bf1, hA, bf0, 0, rowptr, csr_src, dinv);

  // ---- mean pool + head ----
  k_pool2<<<gSEG, H, 0, stream>>>(bf0, batch, pooled);
  k_head<<<NG, OUTC, 0, stream>>>(pooled, gcnt, Wout, bout, out);
}